// Round 1
// baseline (12580.917 us; speedup 1.0000x reference)
//
#include <hip/hip_runtime.h>
#include <hip/hip_bf16.h>

#define N_USER  100000
#define N_ITEM  50000
#define N_NODES 150000
#define NNZ     4800000
#define EMB     64
#define BATCH   16384
#define NEG_SLOPE 0.2f

// ---------------------------------------------------------------- concat ego
__global__ void ngcf_concat(const float4* __restrict__ ue,
                            const float4* __restrict__ ie,
                            float4* __restrict__ ego) {
    const int n4_user  = N_USER * EMB / 4;   // 1.6M
    const int n4_total = N_NODES * EMB / 4;  // 2.4M
    int i = blockIdx.x * blockDim.x + threadIdx.x;
    if (i < n4_total)
        ego[i] = (i < n4_user) ? ue[i] : ie[i - n4_user];
}

// ------------------------------------------------- scatter: side += v*ego[c]
// 16 threads per edge, each handles 4 consecutive floats (float4 gather).
__global__ void ngcf_scatter(const int* __restrict__ rows,
                             const int* __restrict__ cols,
                             const float* __restrict__ vals,
                             const float* __restrict__ ego,
                             float* __restrict__ side) {
    int tid = blockIdx.x * blockDim.x + threadIdx.x;
    int e  = tid >> 4;
    int d  = (tid & 15) * 4;
    if (e >= NNZ) return;
    int   r = rows[e];
    int   c = cols[e];
    float v = vals[e];
    float4 s = *(const float4*)&ego[(size_t)c * EMB + d];
    float* dst = &side[(size_t)r * EMB + d];
    atomicAdd(dst + 0, v * s.x);
    atomicAdd(dst + 1, v * s.y);
    atomicAdd(dst + 2, v * s.z);
    atomicAdd(dst + 3, v * s.w);
}

// ------------------------------------- transform: ego = lrelu(side@Wgc + (ego*side)@Wbi + b)
__global__ __launch_bounds__(256) void ngcf_transform(
        float* __restrict__ ego, const float* __restrict__ side,
        const float* __restrict__ Wgc, const float* __restrict__ bgc,
        const float* __restrict__ Wbi, const float* __restrict__ bbi) {
    __shared__ float sWgc[EMB][EMB];   // 16 KB
    __shared__ float sWbi[EMB][EMB];   // 16 KB
    __shared__ float sb[EMB];
    __shared__ float srow[4][2][EMB];  // per-wave staging: side row, ego*side row

    for (int i = threadIdx.x; i < EMB * EMB; i += blockDim.x) {
        sWgc[i >> 6][i & 63] = Wgc[i];
        sWbi[i >> 6][i & 63] = Wbi[i];
    }
    if (threadIdx.x < EMB) sb[threadIdx.x] = bgc[threadIdx.x] + bbi[threadIdx.x];
    __syncthreads();

    const int wave = threadIdx.x >> 6;
    const int lane = threadIdx.x & 63;
    const int wavesTotal = gridDim.x * 4;

    for (int n = blockIdx.x * 4 + wave; n < N_NODES; n += wavesTotal) {
        float s = side[(size_t)n * EMB + lane];
        float e = ego [(size_t)n * EMB + lane];
        srow[wave][0][lane] = s;
        srow[wave][1][lane] = e * s;   // same-wave LDS use; compiler orders via lgkmcnt
        float acc = sb[lane];
        #pragma unroll
        for (int j = 0; j < EMB; ++j) {
            acc += srow[wave][0][j] * sWgc[j][lane]
                 + srow[wave][1][j] * sWbi[j][lane];
        }
        float out = acc > 0.f ? acc : NEG_SLOPE * acc;
        ego[(size_t)n * EMB + lane] = out;
    }
}

// --------------------------------------------- batch GMF partial accumulation
// one wave per batch element; layer 0 un-normalized, layers 1..3 row-L2-normalized
__global__ void ngcf_batch(const int* __restrict__ uidx,
                           const int* __restrict__ iidx,
                           const float* __restrict__ ego,
                           const float* __restrict__ Wout,
                           float* __restrict__ partial,
                           int layer, int normalize) {
    int b = blockIdx.x * (blockDim.x >> 6) + (threadIdx.x >> 6);
    int lane = threadIdx.x & 63;
    if (b >= BATCH) return;
    int u  = uidx[b];
    int it = N_USER + iidx[b];
    float eu = ego[(size_t)u  * EMB + lane];
    float ei = ego[(size_t)it * EMB + lane];
    float w  = Wout[layer * EMB + lane];
    float dot = eu * ei * w;
    float nu = eu * eu, ni = ei * ei;
    #pragma unroll
    for (int off = 32; off; off >>= 1) {
        dot += __shfl_xor(dot, off);
        nu  += __shfl_xor(nu,  off);
        ni  += __shfl_xor(ni,  off);
    }
    if (lane == 0) {
        float val;
        if (normalize) {
            float denom = fmaxf(sqrtf(nu), 1e-12f) * fmaxf(sqrtf(ni), 1e-12f);
            val = dot / denom;
        } else {
            val = dot;
        }
        if (layer == 0) partial[b] = val;      // init (ws is poisoned)
        else            partial[b] += val;
    }
}

// ----------------------------------------------------------------- sigmoid
__global__ void ngcf_final(const float* __restrict__ partial,
                           const float* __restrict__ bout,
                           float* __restrict__ out) {
    int b = blockIdx.x * blockDim.x + threadIdx.x;
    if (b < BATCH) {
        float x = partial[b] + bout[0];
        out[b] = 1.f / (1.f + expf(-x));
    }
}

extern "C" void kernel_launch(void* const* d_in, const int* in_sizes, int n_in,
                              void* d_out, int out_size, void* d_ws, size_t ws_size,
                              hipStream_t stream) {
    const int*   user_idx = (const int*)  d_in[0];
    const int*   item_idx = (const int*)  d_in[1];
    const int*   adj_rows = (const int*)  d_in[2];
    const int*   adj_cols = (const int*)  d_in[3];
    const float* adj_vals = (const float*)d_in[4];
    const float* user_emb = (const float*)d_in[5];
    const float* item_emb = (const float*)d_in[6];
    const float* W_gc     = (const float*)d_in[7];
    const float* b_gc     = (const float*)d_in[8];
    const float* W_bi     = (const float*)d_in[9];
    const float* b_bi     = (const float*)d_in[10];
    const float* W_out    = (const float*)d_in[11];
    const float* b_out    = (const float*)d_in[12];
    float* out = (float*)d_out;

    float* ego     = (float*)d_ws;                       // 9.6M floats
    float* side    = ego  + (size_t)N_NODES * EMB;       // 9.6M floats
    float* partial = side + (size_t)N_NODES * EMB;       // 16384 floats

    ngcf_concat<<<(N_NODES * EMB / 4 + 255) / 256, 256, 0, stream>>>(
        (const float4*)user_emb, (const float4*)item_emb, (float4*)ego);

    ngcf_batch<<<BATCH / 4, 256, 0, stream>>>(user_idx, item_idx, ego, W_out,
                                              partial, 0, 0);

    for (int k = 0; k < 3; ++k) {
        hipMemsetAsync(side, 0, (size_t)N_NODES * EMB * sizeof(float), stream);
        ngcf_scatter<<<(NNZ * 16) / 256, 256, 0, stream>>>(
            adj_rows, adj_cols, adj_vals, ego, side);
        ngcf_transform<<<2048, 256, 0, stream>>>(
            ego, side, W_gc + k * EMB * EMB, b_gc + k * EMB,
            W_bi + k * EMB * EMB, b_bi + k * EMB);
        ngcf_batch<<<BATCH / 4, 256, 0, stream>>>(user_idx, item_idx, ego, W_out,
                                                  partial, k + 1, 1);
    }

    ngcf_final<<<(BATCH + 255) / 256, 256, 0, stream>>>(partial, b_out, out);
}

// Round 2
// 2429.658 us; speedup vs baseline: 5.1781x; 5.1781x over previous
//
#include <hip/hip_runtime.h>
#include <hip/hip_bf16.h>

#define N_USER  100000
#define N_ITEM  50000
#define N_NODES 150000
#define NNZ     4800000
#define EMB     64
#define BATCH   16384
#define NEG_SLOPE 0.2f
#define SCAN_T  1024

// ---------------------------------------------------------------- concat ego
__global__ void ngcf_concat(const float4* __restrict__ ue,
                            const float4* __restrict__ ie,
                            float4* __restrict__ ego) {
    const int n4_user  = N_USER * EMB / 4;
    const int n4_total = N_NODES * EMB / 4;
    int i = blockIdx.x * blockDim.x + threadIdx.x;
    if (i < n4_total)
        ego[i] = (i < n4_user) ? ue[i] : ie[i - n4_user];
}

// ------------------------------------------------------------- edge histogram
__global__ void ngcf_hist(const int* __restrict__ rows, int* __restrict__ counts) {
    int e = blockIdx.x * blockDim.x + threadIdx.x;
    if (e < NNZ) atomicAdd(&counts[rows[e]], 1);
}

// ----------------------------------- single-block exclusive scan of 150K bins
// counts is REUSED as the bucket cursor (cursor[i] = offs[i]) implicitly:
// we write offs[] and leave counts[] as-is; bucket uses a separate cursor copy
// Actually: we overwrite counts[i] with the exclusive prefix (cursor role).
__global__ void ngcf_scan(int* __restrict__ counts, int* __restrict__ offs) {
    __shared__ int part[SCAN_T];
    int t = threadIdx.x;
    const int chunk = (N_NODES + SCAN_T - 1) / SCAN_T;   // 147
    int lo = t * chunk;
    int hi = lo + chunk; if (hi > N_NODES) hi = N_NODES;
    int s = 0;
    for (int i = lo; i < hi; ++i) s += counts[i];
    part[t] = s;
    __syncthreads();
    for (int d = 1; d < SCAN_T; d <<= 1) {
        int v = (t >= d) ? part[t - d] : 0;
        __syncthreads();
        part[t] += v;
        __syncthreads();
    }
    int run = (t == 0) ? 0 : part[t - 1];
    for (int i = lo; i < hi; ++i) {
        int cnt = counts[i];
        offs[i]   = run;
        counts[i] = run;      // becomes the bucket cursor
        run += cnt;
    }
    if (t == SCAN_T - 1) offs[N_NODES] = run;   // == NNZ
}

// --------------------------------------------------- bucket-scatter edge data
__global__ void ngcf_bucket(const int* __restrict__ rows,
                            const int* __restrict__ cols,
                            const float* __restrict__ vals,
                            int* __restrict__ cursor,
                            int* __restrict__ scol,
                            float* __restrict__ sval) {
    int e = blockIdx.x * blockDim.x + threadIdx.x;
    if (e >= NNZ) return;
    int pos = atomicAdd(&cursor[rows[e]], 1);
    scol[pos] = cols[e];
    sval[pos] = vals[e];
}

// ------------------- fused gather-SpMM + transform (one wave per node row)
// dst[n] = lrelu( side@Wgc + (src[n]*side)@Wbi + b ),  side = sum_e v*src[c]
__global__ __launch_bounds__(256) void ngcf_spmm_transform(
        const float* __restrict__ src, float* __restrict__ dst,
        const int* __restrict__ offs,
        const int* __restrict__ scol, const float* __restrict__ sval,
        const float* __restrict__ Wgc, const float* __restrict__ bgc,
        const float* __restrict__ Wbi, const float* __restrict__ bbi) {
    __shared__ float sWgc[EMB][EMB];   // 16 KB
    __shared__ float sWbi[EMB][EMB];   // 16 KB
    __shared__ float sb[EMB];
    __shared__ float srow[4][2][EMB];  // 2 KB

    for (int i = threadIdx.x; i < EMB * EMB; i += blockDim.x) {
        sWgc[i >> 6][i & 63] = Wgc[i];
        sWbi[i >> 6][i & 63] = Wbi[i];
    }
    if (threadIdx.x < EMB) sb[threadIdx.x] = bgc[threadIdx.x] + bbi[threadIdx.x];
    __syncthreads();

    const int wave = threadIdx.x >> 6;
    const int lane = threadIdx.x & 63;
    const int n = blockIdx.x * 4 + wave;          // grid covers N_NODES exactly
    if (n >= N_NODES) return;

    const int start = offs[n];
    const int end   = offs[n + 1];

    float acc = 0.f;
    int e = start;
    for (; e + 4 <= end; e += 4) {               // 4 loads in flight
        int   c0 = scol[e],     c1 = scol[e + 1];
        int   c2 = scol[e + 2], c3 = scol[e + 3];
        float v0 = sval[e],     v1 = sval[e + 1];
        float v2 = sval[e + 2], v3 = sval[e + 3];
        float x0 = src[((size_t)c0 << 6) + lane];
        float x1 = src[((size_t)c1 << 6) + lane];
        float x2 = src[((size_t)c2 << 6) + lane];
        float x3 = src[((size_t)c3 << 6) + lane];
        acc += v0 * x0 + v1 * x1 + v2 * x2 + v3 * x3;
    }
    for (; e < end; ++e)
        acc += sval[e] * src[((size_t)scol[e] << 6) + lane];

    float ego_v = src[((size_t)n << 6) + lane];
    srow[wave][0][lane] = acc;            // side
    srow[wave][1][lane] = ego_v * acc;    // ego * side  (same-wave LDS)

    float o = sb[lane];
    #pragma unroll
    for (int j = 0; j < EMB; ++j) {
        o += srow[wave][0][j] * sWgc[j][lane]
           + srow[wave][1][j] * sWbi[j][lane];
    }
    o = o > 0.f ? o : NEG_SLOPE * o;
    dst[((size_t)n << 6) + lane] = o;
}

// --------------------------------------------- batch GMF partial accumulation
__global__ void ngcf_batch(const int* __restrict__ uidx,
                           const int* __restrict__ iidx,
                           const float* __restrict__ ego,
                           const float* __restrict__ Wout,
                           float* __restrict__ partial,
                           int layer, int normalize) {
    int b = blockIdx.x * (blockDim.x >> 6) + (threadIdx.x >> 6);
    int lane = threadIdx.x & 63;
    if (b >= BATCH) return;
    int u  = uidx[b];
    int it = N_USER + iidx[b];
    float eu = ego[(size_t)u  * EMB + lane];
    float ei = ego[(size_t)it * EMB + lane];
    float w  = Wout[layer * EMB + lane];
    float dot = eu * ei * w;
    float nu = eu * eu, ni = ei * ei;
    #pragma unroll
    for (int off = 32; off; off >>= 1) {
        dot += __shfl_xor(dot, off);
        nu  += __shfl_xor(nu,  off);
        ni  += __shfl_xor(ni,  off);
    }
    if (lane == 0) {
        float val;
        if (normalize) {
            float denom = fmaxf(sqrtf(nu), 1e-12f) * fmaxf(sqrtf(ni), 1e-12f);
            val = dot / denom;
        } else {
            val = dot;
        }
        if (layer == 0) partial[b] = val;
        else            partial[b] += val;
    }
}

// ----------------------------------------------------------------- sigmoid
__global__ void ngcf_final(const float* __restrict__ partial,
                           const float* __restrict__ bout,
                           float* __restrict__ out) {
    int b = blockIdx.x * blockDim.x + threadIdx.x;
    if (b < BATCH) {
        float x = partial[b] + bout[0];
        out[b] = 1.f / (1.f + expf(-x));
    }
}

// ======================= fallback (R1 atomic-scatter path) ==================
__global__ void ngcf_scatter(const int* __restrict__ rows,
                             const int* __restrict__ cols,
                             const float* __restrict__ vals,
                             const float* __restrict__ ego,
                             float* __restrict__ side) {
    int tid = blockIdx.x * blockDim.x + threadIdx.x;
    int e  = tid >> 4;
    int d  = (tid & 15) * 4;
    if (e >= NNZ) return;
    int   r = rows[e];
    int   c = cols[e];
    float v = vals[e];
    float4 s = *(const float4*)&ego[(size_t)c * EMB + d];
    float* dst = &side[(size_t)r * EMB + d];
    atomicAdd(dst + 0, v * s.x);
    atomicAdd(dst + 1, v * s.y);
    atomicAdd(dst + 2, v * s.z);
    atomicAdd(dst + 3, v * s.w);
}

__global__ __launch_bounds__(256) void ngcf_transform(
        float* __restrict__ ego, const float* __restrict__ side,
        const float* __restrict__ Wgc, const float* __restrict__ bgc,
        const float* __restrict__ Wbi, const float* __restrict__ bbi) {
    __shared__ float sWgc[EMB][EMB];
    __shared__ float sWbi[EMB][EMB];
    __shared__ float sb[EMB];
    __shared__ float srow[4][2][EMB];
    for (int i = threadIdx.x; i < EMB * EMB; i += blockDim.x) {
        sWgc[i >> 6][i & 63] = Wgc[i];
        sWbi[i >> 6][i & 63] = Wbi[i];
    }
    if (threadIdx.x < EMB) sb[threadIdx.x] = bgc[threadIdx.x] + bbi[threadIdx.x];
    __syncthreads();
    const int wave = threadIdx.x >> 6;
    const int lane = threadIdx.x & 63;
    const int wavesTotal = gridDim.x * 4;
    for (int n = blockIdx.x * 4 + wave; n < N_NODES; n += wavesTotal) {
        float s = side[(size_t)n * EMB + lane];
        float e = ego [(size_t)n * EMB + lane];
        srow[wave][0][lane] = s;
        srow[wave][1][lane] = e * s;
        float acc = sb[lane];
        #pragma unroll
        for (int j = 0; j < EMB; ++j) {
            acc += srow[wave][0][j] * sWgc[j][lane]
                 + srow[wave][1][j] * sWbi[j][lane];
        }
        float out = acc > 0.f ? acc : NEG_SLOPE * acc;
        ego[(size_t)n * EMB + lane] = out;
    }
}
// ============================================================================

extern "C" void kernel_launch(void* const* d_in, const int* in_sizes, int n_in,
                              void* d_out, int out_size, void* d_ws, size_t ws_size,
                              hipStream_t stream) {
    const int*   user_idx = (const int*)  d_in[0];
    const int*   item_idx = (const int*)  d_in[1];
    const int*   adj_rows = (const int*)  d_in[2];
    const int*   adj_cols = (const int*)  d_in[3];
    const float* adj_vals = (const float*)d_in[4];
    const float* user_emb = (const float*)d_in[5];
    const float* item_emb = (const float*)d_in[6];
    const float* W_gc     = (const float*)d_in[7];
    const float* b_gc     = (const float*)d_in[8];
    const float* W_bi     = (const float*)d_in[9];
    const float* b_bi     = (const float*)d_in[10];
    const float* W_out    = (const float*)d_in[11];
    const float* b_out    = (const float*)d_in[12];
    float* out = (float*)d_out;

    const size_t NODE_F = (size_t)N_NODES * EMB;           // 9.6M floats
    // fast-path layout
    const size_t need = (2 * NODE_F + N_NODES + (N_NODES + 1) + 2 * (size_t)NNZ
                         + BATCH + 64) * sizeof(float);

    if (ws_size >= need) {
        float* ego0    = (float*)d_ws;
        float* ego1    = ego0 + NODE_F;
        int*   counts  = (int*)(ego1 + NODE_F);
        int*   offs    = counts + N_NODES;
        int*   scol    = offs + (N_NODES + 1);
        float* sval    = (float*)(scol + NNZ);
        float* partial = sval + NNZ;

        ngcf_concat<<<(N_NODES * EMB / 4 + 255) / 256, 256, 0, stream>>>(
            (const float4*)user_emb, (const float4*)item_emb, (float4*)ego0);

        hipMemsetAsync(counts, 0, N_NODES * sizeof(int), stream);
        ngcf_hist  <<<(NNZ + 255) / 256, 256, 0, stream>>>(adj_rows, counts);
        ngcf_scan  <<<1, SCAN_T, 0, stream>>>(counts, offs);
        ngcf_bucket<<<(NNZ + 255) / 256, 256, 0, stream>>>(
            adj_rows, adj_cols, adj_vals, counts, scol, sval);

        ngcf_batch<<<BATCH / 4, 256, 0, stream>>>(user_idx, item_idx, ego0,
                                                  W_out, partial, 0, 0);

        float* src = ego0;
        float* dst = ego1;
        for (int k = 0; k < 3; ++k) {
            ngcf_spmm_transform<<<(N_NODES + 3) / 4, 256, 0, stream>>>(
                src, dst, offs, scol, sval,
                W_gc + k * EMB * EMB, b_gc + k * EMB,
                W_bi + k * EMB * EMB, b_bi + k * EMB);
            ngcf_batch<<<BATCH / 4, 256, 0, stream>>>(user_idx, item_idx, dst,
                                                      W_out, partial, k + 1, 1);
            float* t = src; src = dst; dst = t;
        }
        ngcf_final<<<(BATCH + 255) / 256, 256, 0, stream>>>(partial, b_out, out);
    } else {
        // fallback: R1 atomic path (needs 2*NODE_F + BATCH floats)
        float* ego     = (float*)d_ws;
        float* side    = ego  + NODE_F;
        float* partial = side + NODE_F;

        ngcf_concat<<<(N_NODES * EMB / 4 + 255) / 256, 256, 0, stream>>>(
            (const float4*)user_emb, (const float4*)item_emb, (float4*)ego);
        ngcf_batch<<<BATCH / 4, 256, 0, stream>>>(user_idx, item_idx, ego,
                                                  W_out, partial, 0, 0);
        for (int k = 0; k < 3; ++k) {
            hipMemsetAsync(side, 0, NODE_F * sizeof(float), stream);
            ngcf_scatter<<<(NNZ * 16) / 256, 256, 0, stream>>>(
                adj_rows, adj_cols, adj_vals, ego, side);
            ngcf_transform<<<2048, 256, 0, stream>>>(
                ego, side, W_gc + k * EMB * EMB, b_gc + k * EMB,
                W_bi + k * EMB * EMB, b_bi + k * EMB);
            ngcf_batch<<<BATCH / 4, 256, 0, stream>>>(user_idx, item_idx, ego,
                                                      W_out, partial, k + 1, 1);
        }
        ngcf_final<<<(BATCH + 255) / 256, 256, 0, stream>>>(partial, b_out, out);
    }
}

// Round 3
// 1467.439 us; speedup vs baseline: 8.5734x; 1.6557x over previous
//
#include <hip/hip_runtime.h>

#define N_USER  100000
#define N_ITEM  50000
#define N_NODES 150000
#define NNZ     4800000
#define EMB     64
#define BATCH   16384
#define NEG_SLOPE 0.2f

typedef unsigned int  uint;
typedef unsigned short u16;

static __device__ __forceinline__ u16 f2bf(float f) {
    uint u = __float_as_uint(f);
    return (u16)((u + 0x7fffu + ((u >> 16) & 1u)) >> 16);   // RNE
}
static __device__ __forceinline__ float bf2f(u16 h) {
    return __uint_as_float((uint)h << 16);
}

// ---------------------------------------------------- concat ego (f32->bf16)
__global__ void ngcf_concat(const float4* __restrict__ ue,
                            const float4* __restrict__ ie,
                            ushort4* __restrict__ ego) {
    const int n4_user  = N_USER * EMB / 4;
    const int n4_total = N_NODES * EMB / 4;
    int i = blockIdx.x * blockDim.x + threadIdx.x;
    if (i >= n4_total) return;
    float4 v = (i < n4_user) ? ue[i] : ie[i - n4_user];
    ushort4 o;
    o.x = f2bf(v.x); o.y = f2bf(v.y); o.z = f2bf(v.z); o.w = f2bf(v.w);
    ego[i] = o;
}

// ------------------------------------------------------------- edge histogram
__global__ void ngcf_hist(const int* __restrict__ rows, int* __restrict__ counts) {
    int e = blockIdx.x * blockDim.x + threadIdx.x;
    if (e < NNZ) atomicAdd(&counts[rows[e]], 1);
}

// -------------------------------------------- hierarchical scan (coalesced)
// A: per-256-block sums
__global__ void ngcf_scanA(const int* __restrict__ counts, int* __restrict__ bsum) {
    __shared__ int ws[4];
    int idx = blockIdx.x * 256 + threadIdx.x;
    int v = (idx < N_NODES) ? counts[idx] : 0;
    int lane = threadIdx.x & 63, wave = threadIdx.x >> 6;
    #pragma unroll
    for (int off = 32; off; off >>= 1) v += __shfl_xor(v, off);
    if (lane == 0) ws[wave] = v;
    __syncthreads();
    if (threadIdx.x == 0)
        bsum[blockIdx.x] = ws[0] + ws[1] + ws[2] + ws[3];
}
// B: single-block exclusive scan of the 586 block sums (padded to 1024)
__global__ void ngcf_scanB(int* __restrict__ bsum, int nb, int* __restrict__ total) {
    __shared__ int s[1024];
    int t = threadIdx.x;
    int v = (t < nb) ? bsum[t] : 0;
    s[t] = v;
    __syncthreads();
    for (int d = 1; d < 1024; d <<= 1) {
        int u = (t >= d) ? s[t - d] : 0;
        __syncthreads();
        s[t] += u;
        __syncthreads();
    }
    if (t < nb) bsum[t] = s[t] - v;          // exclusive
    if (t == 1023) *total = s[1023];
}
// C: per-block exclusive scan + base; writes offs[] and cursor[]
__global__ void ngcf_scanC(const int* __restrict__ counts,
                           const int* __restrict__ bsum,
                           const int* __restrict__ total,
                           int* __restrict__ offs, int* __restrict__ cursor) {
    __shared__ int ws[4];
    int idx = blockIdx.x * 256 + threadIdx.x;
    int lane = threadIdx.x & 63, wave = threadIdx.x >> 6;
    int orig = (idx < N_NODES) ? counts[idx] : 0;
    int v = orig;
    #pragma unroll
    for (int off = 1; off < 64; off <<= 1) {
        int u = __shfl_up(v, off);
        if (lane >= off) v += u;
    }
    if (lane == 63) ws[wave] = v;
    __syncthreads();
    int base = bsum[blockIdx.x];
    for (int w = 0; w < 4; ++w) base += (w < wave) ? ws[w] : 0;
    int excl = base + v - orig;
    if (idx < N_NODES) { offs[idx] = excl; cursor[idx] = excl; }
    if (blockIdx.x == 0 && threadIdx.x == 0) offs[N_NODES] = *total;
}

// --------------------------------------------------- bucket-scatter edge data
__global__ void ngcf_bucket(const int* __restrict__ rows,
                            const int* __restrict__ cols,
                            const float* __restrict__ vals,
                            int* __restrict__ cursor,
                            int2* __restrict__ edges) {
    int e = blockIdx.x * blockDim.x + threadIdx.x;
    if (e >= NNZ) return;
    int pos = atomicAdd(&cursor[rows[e]], 1);
    int2 E; E.x = cols[e]; E.y = __float_as_int(vals[e]);
    edges[pos] = E;
}

// ---------------- fused gather-SpMM + shfl-transform (one wave per node row)
// dst[n] = bf16( lrelu( side@Wgc + (src[n]*side)@Wbi + bgc+bbi ) )
__global__ __launch_bounds__(256) void ngcf_spmm_fused(
        const u16* __restrict__ src, u16* __restrict__ dst,
        const int* __restrict__ offs, const int2* __restrict__ edges,
        const float* __restrict__ Wgc, const float* __restrict__ bgc,
        const float* __restrict__ Wbi, const float* __restrict__ bbi) {
    const int wave = threadIdx.x >> 6;
    const int lane = threadIdx.x & 63;
    const int n = blockIdx.x * 4 + wave;
    if (n >= N_NODES) return;

    const int start = offs[n];
    const int end   = offs[n + 1];

    float acc = 0.f;
    int e = start;
    for (; e + 8 <= end; e += 8) {
        int2 E0 = edges[e],     E1 = edges[e + 1];
        int2 E2 = edges[e + 2], E3 = edges[e + 3];
        int2 E4 = edges[e + 4], E5 = edges[e + 5];
        int2 E6 = edges[e + 6], E7 = edges[e + 7];
        float x0 = bf2f(src[((size_t)E0.x << 6) + lane]);
        float x1 = bf2f(src[((size_t)E1.x << 6) + lane]);
        float x2 = bf2f(src[((size_t)E2.x << 6) + lane]);
        float x3 = bf2f(src[((size_t)E3.x << 6) + lane]);
        float x4 = bf2f(src[((size_t)E4.x << 6) + lane]);
        float x5 = bf2f(src[((size_t)E5.x << 6) + lane]);
        float x6 = bf2f(src[((size_t)E6.x << 6) + lane]);
        float x7 = bf2f(src[((size_t)E7.x << 6) + lane]);
        acc += __int_as_float(E0.y) * x0 + __int_as_float(E1.y) * x1
             + __int_as_float(E2.y) * x2 + __int_as_float(E3.y) * x3
             + __int_as_float(E4.y) * x4 + __int_as_float(E5.y) * x5
             + __int_as_float(E6.y) * x6 + __int_as_float(E7.y) * x7;
    }
    for (; e < end; ++e) {
        int2 E = edges[e];
        acc += __int_as_float(E.y) * bf2f(src[((size_t)E.x << 6) + lane]);
    }

    float ego_v = bf2f(src[((size_t)n << 6) + lane]);
    float bi = ego_v * acc;                    // (ego * side)[lane]
    float o = bgc[lane] + bbi[lane];
    #pragma unroll
    for (int j = 0; j < EMB; ++j) {
        float sj = __shfl(acc, j);
        float bj = __shfl(bi,  j);
        o += sj * Wgc[(j << 6) + lane] + bj * Wbi[(j << 6) + lane];
    }
    o = o > 0.f ? o : NEG_SLOPE * o;
    dst[((size_t)n << 6) + lane] = f2bf(o);
}

// --------------------------------------------- batch GMF partial accumulation
__global__ void ngcf_batch(const int* __restrict__ uidx,
                           const int* __restrict__ iidx,
                           const u16* __restrict__ ego,
                           const float* __restrict__ Wout,
                           float* __restrict__ partial,
                           int layer, int normalize) {
    int b = blockIdx.x * (blockDim.x >> 6) + (threadIdx.x >> 6);
    int lane = threadIdx.x & 63;
    if (b >= BATCH) return;
    int u  = uidx[b];
    int it = N_USER + iidx[b];
    float eu = bf2f(ego[((size_t)u  << 6) + lane]);
    float ei = bf2f(ego[((size_t)it << 6) + lane]);
    float w  = Wout[(layer << 6) + lane];
    float dot = eu * ei * w;
    float nu = eu * eu, ni = ei * ei;
    #pragma unroll
    for (int off = 32; off; off >>= 1) {
        dot += __shfl_xor(dot, off);
        nu  += __shfl_xor(nu,  off);
        ni  += __shfl_xor(ni,  off);
    }
    if (lane == 0) {
        float val;
        if (normalize) {
            float denom = fmaxf(sqrtf(nu), 1e-12f) * fmaxf(sqrtf(ni), 1e-12f);
            val = dot / denom;
        } else {
            val = dot;
        }
        if (layer == 0) partial[b] = val;
        else            partial[b] += val;
    }
}

// ----------------------------------------------------------------- sigmoid
__global__ void ngcf_final(const float* __restrict__ partial,
                           const float* __restrict__ bout,
                           float* __restrict__ out) {
    int b = blockIdx.x * blockDim.x + threadIdx.x;
    if (b < BATCH) {
        float x = partial[b] + bout[0];
        out[b] = 1.f / (1.f + expf(-x));
    }
}

extern "C" void kernel_launch(void* const* d_in, const int* in_sizes, int n_in,
                              void* d_out, int out_size, void* d_ws, size_t ws_size,
                              hipStream_t stream) {
    const int*   user_idx = (const int*)  d_in[0];
    const int*   item_idx = (const int*)  d_in[1];
    const int*   adj_rows = (const int*)  d_in[2];
    const int*   adj_cols = (const int*)  d_in[3];
    const float* adj_vals = (const float*)d_in[4];
    const float* user_emb = (const float*)d_in[5];
    const float* item_emb = (const float*)d_in[6];
    const float* W_gc     = (const float*)d_in[7];
    const float* b_gc     = (const float*)d_in[8];
    const float* W_bi     = (const float*)d_in[9];
    const float* b_bi     = (const float*)d_in[10];
    const float* W_out    = (const float*)d_in[11];
    const float* b_out    = (const float*)d_in[12];
    float* out = (float*)d_out;

    const size_t NODE_F = (size_t)N_NODES * EMB;   // 9.6M elems
    const int NB = (N_NODES + 255) / 256;          // 586 scan blocks

    // workspace carve-up (256 B aligned segments)
    char* base = (char*)d_ws;
    size_t off = 0;
    auto carve = [&](size_t bytes) {
        char* p = base + off;
        off = (off + bytes + 255) & ~(size_t)255;
        return p;
    };
    u16*   ego0    = (u16*)  carve(NODE_F * 2);
    u16*   ego1    = (u16*)  carve(NODE_F * 2);
    int*   counts  = (int*)  carve(N_NODES * 4);
    int*   cursor  = (int*)  carve(N_NODES * 4);
    int*   offs    = (int*)  carve((N_NODES + 1) * 4);
    int*   bsum    = (int*)  carve(1024 * 4);
    int*   total   = (int*)  carve(64);
    int2*  edges   = (int2*) carve((size_t)NNZ * 8);
    float* partial = (float*)carve(BATCH * 4);
    (void)ws_size;

    ngcf_concat<<<(N_NODES * EMB / 4 + 255) / 256, 256, 0, stream>>>(
        (const float4*)user_emb, (const float4*)item_emb, (ushort4*)ego0);

    hipMemsetAsync(counts, 0, N_NODES * sizeof(int), stream);
    ngcf_hist <<<(NNZ + 255) / 256, 256, 0, stream>>>(adj_rows, counts);
    ngcf_scanA<<<NB, 256, 0, stream>>>(counts, bsum);
    ngcf_scanB<<<1, 1024, 0, stream>>>(bsum, NB, total);
    ngcf_scanC<<<NB, 256, 0, stream>>>(counts, bsum, total, offs, cursor);
    ngcf_bucket<<<(NNZ + 255) / 256, 256, 0, stream>>>(
        adj_rows, adj_cols, adj_vals, cursor, edges);

    ngcf_batch<<<BATCH / 4, 256, 0, stream>>>(user_idx, item_idx, ego0,
                                              W_out, partial, 0, 0);

    u16* src = ego0;
    u16* dst = ego1;
    for (int k = 0; k < 3; ++k) {
        ngcf_spmm_fused<<<(N_NODES + 3) / 4, 256, 0, stream>>>(
            src, dst, offs, edges,
            W_gc + k * EMB * EMB, b_gc + k * EMB,
            W_bi + k * EMB * EMB, b_bi + k * EMB);
        ngcf_batch<<<BATCH / 4, 256, 0, stream>>>(user_idx, item_idx, dst,
                                                  W_out, partial, k + 1, 1);
        u16* t = src; src = dst; dst = t;
    }
    ngcf_final<<<(BATCH + 255) / 256, 256, 0, stream>>>(partial, b_out, out);
}

// Round 4
// 1309.781 us; speedup vs baseline: 9.6054x; 1.1204x over previous
//
#include <hip/hip_runtime.h>

#define N_USER  100000
#define N_ITEM  50000
#define N_NODES 150000
#define NNZ     4800000
#define EMB     64
#define BATCH   16384
#define NEG_SLOPE 0.2f

#define NB_C   512                       // coarse buckets
#define NPB    ((N_NODES + NB_C - 1) / NB_C)   // 293 nodes per bucket
#define CHUNK  8192                      // edges per coarse_scatter block
#define NCH    ((NNZ + CHUNK - 1) / CHUNK)     // 586

typedef unsigned int  uint;
typedef unsigned short u16;

static __device__ __forceinline__ u16 f2bf(float f) {
    uint u = __float_as_uint(f);
    return (u16)((u + 0x7fffu + ((u >> 16) & 1u)) >> 16);   // RNE
}
static __device__ __forceinline__ float bf2f(u16 h) {
    return __uint_as_float((uint)h << 16);
}

// ---------------------------------------------------- concat ego (f32->bf16)
__global__ void ngcf_concat(const float4* __restrict__ ue,
                            const float4* __restrict__ ie,
                            ushort4* __restrict__ ego) {
    const int n4_user  = N_USER * EMB / 4;
    const int n4_total = N_NODES * EMB / 4;
    int i = blockIdx.x * blockDim.x + threadIdx.x;
    if (i >= n4_total) return;
    float4 v = (i < n4_user) ? ue[i] : ie[i - n4_user];
    ushort4 o;
    o.x = f2bf(v.x); o.y = f2bf(v.y); o.z = f2bf(v.z); o.w = f2bf(v.w);
    ego[i] = o;
}

// ------------------------------------------- coarse histogram (LDS-aggregated)
__global__ void ngcf_coarse_hist(const int* __restrict__ rows,
                                 int* __restrict__ ccnt) {
    __shared__ int bins[NB_C];
    bins[threadIdx.x] = 0;
    bins[threadIdx.x + 256] = 0;
    __syncthreads();
    int stride = gridDim.x * blockDim.x;
    for (int e = blockIdx.x * blockDim.x + threadIdx.x; e < NNZ; e += stride)
        atomicAdd(&bins[rows[e] / NPB], 1);
    __syncthreads();
    int v0 = bins[threadIdx.x], v1 = bins[threadIdx.x + 256];
    if (v0) atomicAdd(&ccnt[threadIdx.x], v0);
    if (v1) atomicAdd(&ccnt[threadIdx.x + 256], v1);
}

// ------------------------------------ scan of 512 coarse counts (one block)
__global__ void ngcf_coarse_scan(const int* __restrict__ ccnt,
                                 int* __restrict__ coffs,
                                 int* __restrict__ gcursor) {
    __shared__ int wsum[8];
    int t = threadIdx.x, lane = t & 63, wv = t >> 6;
    int v = ccnt[t];
    int inc = v;
    #pragma unroll
    for (int off = 1; off < 64; off <<= 1) {
        int u = __shfl_up(inc, off);
        if (lane >= off) inc += u;
    }
    if (lane == 63) wsum[wv] = inc;
    __syncthreads();
    int base = 0;
    #pragma unroll
    for (int w = 0; w < 8; ++w) base += (w < wv) ? wsum[w] : 0;
    int incl = base + inc;
    int excl = incl - v;
    coffs[t]   = excl;
    gcursor[t] = excl;
    if (t == NB_C - 1) coffs[NB_C] = incl;     // == NNZ
}

// ---------------- coarse scatter: chunk-binned, run-reserved, locally written
__global__ __launch_bounds__(512) void ngcf_coarse_scatter(
        const int* __restrict__ rows, const int* __restrict__ cols,
        const float* __restrict__ vals,
        int* __restrict__ gcursor,
        int2* __restrict__ tmp_cv, u16* __restrict__ tmp_lr) {
    __shared__ int bins[NB_C];
    __shared__ int rbase[NB_C];
    const int t = threadIdx.x;
    const int e0 = blockIdx.x * CHUNK;
    bins[t] = 0;
    __syncthreads();
    // phase A: count
    #pragma unroll
    for (int i = 0; i < CHUNK / 512; ++i) {
        int e = e0 + i * 512 + t;
        if (e < NNZ) atomicAdd(&bins[rows[e] / NPB], 1);
    }
    __syncthreads();
    // phase B: reserve runs (one global atomic per non-empty bucket)
    int c = bins[t];
    if (c > 0) rbase[t] = atomicAdd(&gcursor[t], c);
    bins[t] = 0;                // becomes rank counter
    __syncthreads();
    // phase C: write payload into the reserved runs
    #pragma unroll
    for (int i = 0; i < CHUNK / 512; ++i) {
        int e = e0 + i * 512 + t;
        if (e < NNZ) {
            int r  = rows[e];
            int b  = r / NPB;
            int lr = r - b * NPB;
            int rk = atomicAdd(&bins[b], 1);
            int pos = rbase[b] + rk;
            int2 E; E.x = cols[e]; E.y = __float_as_int(vals[e]);
            tmp_cv[pos] = E;
            tmp_lr[pos] = (u16)lr;
        }
    }
}

// -------------- fine sort: one block per coarse bucket, node-level ordering
__global__ __launch_bounds__(512) void ngcf_fine_sort(
        const int* __restrict__ coffs,
        const int2* __restrict__ tmp_cv, const u16* __restrict__ tmp_lr,
        int* __restrict__ offs, int2* __restrict__ edges) {
    __shared__ int s[512];
    const int b   = blockIdx.x;
    const int t   = threadIdx.x;
    const int nlo = b * NPB;
    const int nhi = min(nlo + NPB, N_NODES);
    const int nn  = nhi - nlo;
    const int clo = coffs[b];
    const int chi = coffs[b + 1];

    s[t] = 0;
    __syncthreads();
    for (int e = clo + t; e < chi; e += 512)
        atomicAdd(&s[tmp_lr[e]], 1);
    __syncthreads();
    int v = s[t];
    // Hillis-Steele inclusive scan over 512
    for (int d = 1; d < 512; d <<= 1) {
        int u = (t >= d) ? s[t - d] : 0;
        __syncthreads();
        s[t] += u;
        __syncthreads();
    }
    int excl = s[t] - v;
    if (t < nn) offs[nlo + t] = clo + excl;
    __syncthreads();
    s[t] = clo + excl;          // becomes per-node cursor
    __syncthreads();
    for (int e = clo + t; e < chi; e += 512) {
        int lr = tmp_lr[e];
        int p  = atomicAdd(&s[lr], 1);
        edges[p] = tmp_cv[e];
    }
    if (b == NB_C - 1 && t == 0) offs[N_NODES] = chi;   // == NNZ
}

// ---------------- fused gather-SpMM + shfl-transform (one wave per node row)
__global__ __launch_bounds__(256) void ngcf_spmm_fused(
        const u16* __restrict__ src, u16* __restrict__ dst,
        const int* __restrict__ offs, const int2* __restrict__ edges,
        const float* __restrict__ Wgc, const float* __restrict__ bgc,
        const float* __restrict__ Wbi, const float* __restrict__ bbi) {
    const int wave = threadIdx.x >> 6;
    const int lane = threadIdx.x & 63;
    const int n = blockIdx.x * 4 + wave;
    if (n >= N_NODES) return;

    const int start = offs[n];
    const int end   = offs[n + 1];

    const long long* ep = (const long long*)edges;
    float acc = 0.f;
    int e = start;
    for (; e + 8 <= end; e += 8) {
        long long L0 = __builtin_nontemporal_load(ep + e);
        long long L1 = __builtin_nontemporal_load(ep + e + 1);
        long long L2 = __builtin_nontemporal_load(ep + e + 2);
        long long L3 = __builtin_nontemporal_load(ep + e + 3);
        long long L4 = __builtin_nontemporal_load(ep + e + 4);
        long long L5 = __builtin_nontemporal_load(ep + e + 5);
        long long L6 = __builtin_nontemporal_load(ep + e + 6);
        long long L7 = __builtin_nontemporal_load(ep + e + 7);
        float x0 = bf2f(src[((size_t)(int)L0 << 6) + lane]);
        float x1 = bf2f(src[((size_t)(int)L1 << 6) + lane]);
        float x2 = bf2f(src[((size_t)(int)L2 << 6) + lane]);
        float x3 = bf2f(src[((size_t)(int)L3 << 6) + lane]);
        float x4 = bf2f(src[((size_t)(int)L4 << 6) + lane]);
        float x5 = bf2f(src[((size_t)(int)L5 << 6) + lane]);
        float x6 = bf2f(src[((size_t)(int)L6 << 6) + lane]);
        float x7 = bf2f(src[((size_t)(int)L7 << 6) + lane]);
        acc += __int_as_float((int)(L0 >> 32)) * x0
             + __int_as_float((int)(L1 >> 32)) * x1
             + __int_as_float((int)(L2 >> 32)) * x2
             + __int_as_float((int)(L3 >> 32)) * x3
             + __int_as_float((int)(L4 >> 32)) * x4
             + __int_as_float((int)(L5 >> 32)) * x5
             + __int_as_float((int)(L6 >> 32)) * x6
             + __int_as_float((int)(L7 >> 32)) * x7;
    }
    for (; e < end; ++e) {
        long long L = __builtin_nontemporal_load(ep + e);
        acc += __int_as_float((int)(L >> 32))
             * bf2f(src[((size_t)(int)L << 6) + lane]);
    }

    float ego_v = bf2f(src[((size_t)n << 6) + lane]);
    float bi = ego_v * acc;
    float o = bgc[lane] + bbi[lane];
    #pragma unroll
    for (int j = 0; j < EMB; ++j) {
        float sj = __shfl(acc, j);
        float bj = __shfl(bi,  j);
        o += sj * Wgc[(j << 6) + lane] + bj * Wbi[(j << 6) + lane];
    }
    o = o > 0.f ? o : NEG_SLOPE * o;
    dst[((size_t)n << 6) + lane] = f2bf(o);
}

// --------------------------------------------- batch GMF partial accumulation
__global__ void ngcf_batch(const int* __restrict__ uidx,
                           const int* __restrict__ iidx,
                           const u16* __restrict__ ego,
                           const float* __restrict__ Wout,
                           float* __restrict__ partial,
                           int layer, int normalize) {
    int b = blockIdx.x * (blockDim.x >> 6) + (threadIdx.x >> 6);
    int lane = threadIdx.x & 63;
    if (b >= BATCH) return;
    int u  = uidx[b];
    int it = N_USER + iidx[b];
    float eu = bf2f(ego[((size_t)u  << 6) + lane]);
    float ei = bf2f(ego[((size_t)it << 6) + lane]);
    float w  = Wout[(layer << 6) + lane];
    float dot = eu * ei * w;
    float nu = eu * eu, ni = ei * ei;
    #pragma unroll
    for (int off = 32; off; off >>= 1) {
        dot += __shfl_xor(dot, off);
        nu  += __shfl_xor(nu,  off);
        ni  += __shfl_xor(ni,  off);
    }
    if (lane == 0) {
        float val;
        if (normalize) {
            float denom = fmaxf(sqrtf(nu), 1e-12f) * fmaxf(sqrtf(ni), 1e-12f);
            val = dot / denom;
        } else {
            val = dot;
        }
        if (layer == 0) partial[b] = val;
        else            partial[b] += val;
    }
}

// ----------------------------------------------------------------- sigmoid
__global__ void ngcf_final(const float* __restrict__ partial,
                           const float* __restrict__ bout,
                           float* __restrict__ out) {
    int b = blockIdx.x * blockDim.x + threadIdx.x;
    if (b < BATCH) {
        float x = partial[b] + bout[0];
        out[b] = 1.f / (1.f + expf(-x));
    }
}

extern "C" void kernel_launch(void* const* d_in, const int* in_sizes, int n_in,
                              void* d_out, int out_size, void* d_ws, size_t ws_size,
                              hipStream_t stream) {
    const int*   user_idx = (const int*)  d_in[0];
    const int*   item_idx = (const int*)  d_in[1];
    const int*   adj_rows = (const int*)  d_in[2];
    const int*   adj_cols = (const int*)  d_in[3];
    const float* adj_vals = (const float*)d_in[4];
    const float* user_emb = (const float*)d_in[5];
    const float* item_emb = (const float*)d_in[6];
    const float* W_gc     = (const float*)d_in[7];
    const float* b_gc     = (const float*)d_in[8];
    const float* W_bi     = (const float*)d_in[9];
    const float* b_bi     = (const float*)d_in[10];
    const float* W_out    = (const float*)d_in[11];
    const float* b_out    = (const float*)d_in[12];
    float* out = (float*)d_out;

    const size_t NODE_F = (size_t)N_NODES * EMB;   // 9.6M elems

    char* base = (char*)d_ws;
    size_t off = 0;
    auto carve = [&](size_t bytes) {
        char* p = base + off;
        off = (off + bytes + 255) & ~(size_t)255;
        return p;
    };
    u16*   ego0    = (u16*)  carve(NODE_F * 2);
    u16*   ego1    = (u16*)  carve(NODE_F * 2);
    int2*  edges   = (int2*) carve((size_t)NNZ * 8);
    int2*  tmp_cv  = (int2*) carve((size_t)NNZ * 8);
    u16*   tmp_lr  = (u16*)  carve((size_t)NNZ * 2);
    int*   offs    = (int*)  carve((N_NODES + 1) * 4);
    int*   ccnt    = (int*)  carve(NB_C * 4);
    int*   coffs   = (int*)  carve((NB_C + 1) * 4);
    int*   gcursor = (int*)  carve(NB_C * 4);
    float* partial = (float*)carve(BATCH * 4);
    (void)ws_size;

    ngcf_concat<<<(N_NODES * EMB / 4 + 255) / 256, 256, 0, stream>>>(
        (const float4*)user_emb, (const float4*)item_emb, (ushort4*)ego0);

    hipMemsetAsync(ccnt, 0, NB_C * sizeof(int), stream);
    ngcf_coarse_hist   <<<1024, 256, 0, stream>>>(adj_rows, ccnt);
    ngcf_coarse_scan   <<<1, NB_C, 0, stream>>>(ccnt, coffs, gcursor);
    ngcf_coarse_scatter<<<NCH, 512, 0, stream>>>(adj_rows, adj_cols, adj_vals,
                                                 gcursor, tmp_cv, tmp_lr);
    ngcf_fine_sort     <<<NB_C, 512, 0, stream>>>(coffs, tmp_cv, tmp_lr,
                                                  offs, edges);

    ngcf_batch<<<BATCH / 4, 256, 0, stream>>>(user_idx, item_idx, ego0,
                                              W_out, partial, 0, 0);

    u16* src = ego0;
    u16* dst = ego1;
    for (int k = 0; k < 3; ++k) {
        ngcf_spmm_fused<<<(N_NODES + 3) / 4, 256, 0, stream>>>(
            src, dst, offs, edges,
            W_gc + k * EMB * EMB, b_gc + k * EMB,
            W_bi + k * EMB * EMB, b_bi + k * EMB);
        ngcf_batch<<<BATCH / 4, 256, 0, stream>>>(user_idx, item_idx, dst,
                                                  W_out, partial, k + 1, 1);
        u16* t = src; src = dst; dst = t;
    }
    ngcf_final<<<(BATCH + 255) / 256, 256, 0, stream>>>(partial, b_out, out);
}

// Round 5
// 1148.384 us; speedup vs baseline: 10.9553x; 1.1405x over previous
//
#include <hip/hip_runtime.h>

#define N_USER  100000
#define N_ITEM  50000
#define N_NODES 150000
#define NNZ     4800000
#define EMB     64
#define BATCH   16384
#define NEG_SLOPE 0.2f

#define NB_C   512                       // coarse buckets
#define NPB    ((N_NODES + NB_C - 1) / NB_C)   // 293 nodes per bucket
#define CHUNK  8192                      // edges per coarse_scatter block
#define NCH    ((NNZ + CHUNK - 1) / CHUNK)     // 586

#define WFRAG_ELEMS (3 * 2 * 2 * 4 * 64 * 8)   // layer,mat,ks,wave,lane,i

typedef unsigned int  uint;
typedef unsigned short u16;
typedef short bf16x8 __attribute__((ext_vector_type(8)));
typedef float f32x4  __attribute__((ext_vector_type(4)));

static __device__ __forceinline__ u16 f2bf(float f) {
    uint u = __float_as_uint(f);
    return (u16)((u + 0x7fffu + ((u >> 16) & 1u)) >> 16);   // RNE
}
static __device__ __forceinline__ float bf2f(u16 h) {
    return __uint_as_float((uint)h << 16);
}

// ---------------------------------------------------- concat ego (f32->bf16)
__global__ void ngcf_concat(const float4* __restrict__ ue,
                            const float4* __restrict__ ie,
                            ushort4* __restrict__ ego) {
    const int n4_user  = N_USER * EMB / 4;
    const int n4_total = N_NODES * EMB / 4;
    int i = blockIdx.x * blockDim.x + threadIdx.x;
    if (i >= n4_total) return;
    float4 v = (i < n4_user) ? ue[i] : ie[i - n4_user];
    ushort4 o;
    o.x = f2bf(v.x); o.y = f2bf(v.y); o.z = f2bf(v.z); o.w = f2bf(v.w);
    ego[i] = o;
}

// ------------- prep: W -> bf16 fragments in MFMA B-layout; bias = bgc + bbi
// wfrag index: ((((layer*2+mat)*2+ks)*4+w)*64+lane)*8+i
//   k = ks*32 + (lane>>4)*8 + i ; n = w*16 + (lane&15) ; elem = W[layer][k][n]
__global__ void ngcf_prep(const float* __restrict__ Wgc,
                          const float* __restrict__ Wbi,
                          const float* __restrict__ bgc,
                          const float* __restrict__ bbi,
                          u16* __restrict__ wfrag, float* __restrict__ bias) {
    int t = blockIdx.x * blockDim.x + threadIdx.x;
    if (t < WFRAG_ELEMS) {
        int i     = t & 7;
        int lane  = (t >> 3) & 63;
        int w     = (t >> 9) & 3;
        int ks    = (t >> 11) & 1;
        int mat   = (t >> 12) & 1;
        int layer = t >> 13;
        int k = ks * 32 + (lane >> 4) * 8 + i;
        int n = w * 16 + (lane & 15);
        const float* W = mat ? Wbi : Wgc;
        wfrag[t] = f2bf(W[(layer * 64 + k) * 64 + n]);
    }
    int u = t - WFRAG_ELEMS;
    if (u >= 0 && u < 3 * 64)
        bias[u] = bgc[u] + bbi[u];
}

// ------------------------------------------- coarse histogram (LDS-aggregated)
__global__ void ngcf_coarse_hist(const int* __restrict__ rows,
                                 int* __restrict__ ccnt) {
    __shared__ int bins[NB_C];
    bins[threadIdx.x] = 0;
    bins[threadIdx.x + 256] = 0;
    __syncthreads();
    int stride = gridDim.x * blockDim.x;
    for (int e = blockIdx.x * blockDim.x + threadIdx.x; e < NNZ; e += stride)
        atomicAdd(&bins[rows[e] / NPB], 1);
    __syncthreads();
    int v0 = bins[threadIdx.x], v1 = bins[threadIdx.x + 256];
    if (v0) atomicAdd(&ccnt[threadIdx.x], v0);
    if (v1) atomicAdd(&ccnt[threadIdx.x + 256], v1);
}

// ------------------------------------ scan of 512 coarse counts (one block)
__global__ void ngcf_coarse_scan(const int* __restrict__ ccnt,
                                 int* __restrict__ coffs,
                                 int* __restrict__ gcursor) {
    __shared__ int wsum[8];
    int t = threadIdx.x, lane = t & 63, wv = t >> 6;
    int v = ccnt[t];
    int inc = v;
    #pragma unroll
    for (int off = 1; off < 64; off <<= 1) {
        int u = __shfl_up(inc, off);
        if (lane >= off) inc += u;
    }
    if (lane == 63) wsum[wv] = inc;
    __syncthreads();
    int base = 0;
    #pragma unroll
    for (int w = 0; w < 8; ++w) base += (w < wv) ? wsum[w] : 0;
    int incl = base + inc;
    int excl = incl - v;
    coffs[t]   = excl;
    gcursor[t] = excl;
    if (t == NB_C - 1) coffs[NB_C] = incl;     // == NNZ
}

// ---------------- coarse scatter: chunk-binned, run-reserved, locally written
__global__ __launch_bounds__(512) void ngcf_coarse_scatter(
        const int* __restrict__ rows, const int* __restrict__ cols,
        const float* __restrict__ vals,
        int* __restrict__ gcursor,
        int2* __restrict__ tmp_cv, u16* __restrict__ tmp_lr) {
    __shared__ int bins[NB_C];
    __shared__ int rbase[NB_C];
    const int t = threadIdx.x;
    const int e0 = blockIdx.x * CHUNK;
    bins[t] = 0;
    __syncthreads();
    #pragma unroll
    for (int i = 0; i < CHUNK / 512; ++i) {
        int e = e0 + i * 512 + t;
        if (e < NNZ) atomicAdd(&bins[rows[e] / NPB], 1);
    }
    __syncthreads();
    int c = bins[t];
    if (c > 0) rbase[t] = atomicAdd(&gcursor[t], c);
    bins[t] = 0;
    __syncthreads();
    #pragma unroll
    for (int i = 0; i < CHUNK / 512; ++i) {
        int e = e0 + i * 512 + t;
        if (e < NNZ) {
            int r  = rows[e];
            int b  = r / NPB;
            int lr = r - b * NPB;
            int rk = atomicAdd(&bins[b], 1);
            int pos = rbase[b] + rk;
            int2 E; E.x = cols[e]; E.y = __float_as_int(vals[e]);
            tmp_cv[pos] = E;
            tmp_lr[pos] = (u16)lr;
        }
    }
}

// -------------- fine sort: one block per coarse bucket, node-level ordering
__global__ __launch_bounds__(512) void ngcf_fine_sort(
        const int* __restrict__ coffs,
        const int2* __restrict__ tmp_cv, const u16* __restrict__ tmp_lr,
        int* __restrict__ offs, int2* __restrict__ edges) {
    __shared__ int s[512];
    const int b   = blockIdx.x;
    const int t   = threadIdx.x;
    const int nlo = b * NPB;
    const int nhi = min(nlo + NPB, N_NODES);
    const int nn  = nhi - nlo;
    const int clo = coffs[b];
    const int chi = coffs[b + 1];

    s[t] = 0;
    __syncthreads();
    for (int e = clo + t; e < chi; e += 512)
        atomicAdd(&s[tmp_lr[e]], 1);
    __syncthreads();
    int v = s[t];
    for (int d = 1; d < 512; d <<= 1) {
        int u = (t >= d) ? s[t - d] : 0;
        __syncthreads();
        s[t] += u;
        __syncthreads();
    }
    int excl = s[t] - v;
    if (t < nn) offs[nlo + t] = clo + excl;
    __syncthreads();
    s[t] = clo + excl;
    __syncthreads();
    for (int e = clo + t; e < chi; e += 512) {
        int lr = tmp_lr[e];
        int p  = atomicAdd(&s[lr], 1);
        edges[p] = tmp_cv[e];
    }
    if (b == NB_C - 1 && t == 0) offs[N_NODES] = chi;
}

// ---------------- fused gather-SpMM + MFMA transform (16 nodes per block)
// wave handles 4 nodes (16 lanes x ushort4 = full 128B row per group), then
// block does [16x64] @ [64x64] x2 via mfma_f32_16x16x32_bf16.
__global__ __launch_bounds__(256) void ngcf_spmm_mfma(
        const u16* __restrict__ src, u16* __restrict__ dst,
        const int* __restrict__ offs, const int2* __restrict__ edges,
        const u16* __restrict__ wfrag, const float* __restrict__ bias,
        int layer) {
    __shared__ float sideL[16][68];   // +4 pad: bank-spread & 16B alignment
    __shared__ float biL[16][68];

    const int wave = threadIdx.x >> 6;
    const int lane = threadIdx.x & 63;
    const int g    = lane >> 4;        // node group 0..3
    const int q    = lane & 15;        // dim quad: dims 4q..4q+3
    const int node = blockIdx.x * 16 + wave * 4 + g;

    const int sBeg = offs[node];
    const int deg  = offs[node + 1] - sBeg;

    const long long* ep  = (const long long*)edges;
    const ushort4*   s4p = (const ushort4*)src;

    float a0 = 0.f, a1 = 0.f, a2 = 0.f, a3 = 0.f;
    for (int e = 0; __any(e < deg); e += 2) {
        if (e < deg) {
            long long E = __builtin_nontemporal_load(ep + sBeg + e);
            int   c = (int)E;
            float v = __int_as_float((int)(E >> 32));
            ushort4 s4 = s4p[(size_t)c * 16 + q];
            a0 += v * bf2f(s4.x); a1 += v * bf2f(s4.y);
            a2 += v * bf2f(s4.z); a3 += v * bf2f(s4.w);
        }
        if (e + 1 < deg) {
            long long E = __builtin_nontemporal_load(ep + sBeg + e + 1);
            int   c = (int)E;
            float v = __int_as_float((int)(E >> 32));
            ushort4 s4 = s4p[(size_t)c * 16 + q];
            a0 += v * bf2f(s4.x); a1 += v * bf2f(s4.y);
            a2 += v * bf2f(s4.z); a3 += v * bf2f(s4.w);
        }
    }

    ushort4 egov = s4p[(size_t)node * 16 + q];
    const int r = wave * 4 + g;
    float4 sv; sv.x = a0; sv.y = a1; sv.z = a2; sv.w = a3;
    float4 bv; bv.x = bf2f(egov.x) * a0; bv.y = bf2f(egov.y) * a1;
    bv.z = bf2f(egov.z) * a2; bv.w = bf2f(egov.w) * a3;
    *(float4*)&sideL[r][4 * q] = sv;
    *(float4*)&biL[r][4 * q]   = bv;
    __syncthreads();

    // ---- MFMA transform: wave covers out-cols [wave*16, wave*16+16)
    const int m  = lane & 15;          // A row (node) held by this lane
    const int kh = lane >> 4;          // k-half index
    f32x4 acc = {0.f, 0.f, 0.f, 0.f};
    const bf16x8* wf = (const bf16x8*)wfrag;

    #pragma unroll
    for (int ks = 0; ks < 2; ++ks) {
        const int k0 = ks * 32 + kh * 8;
        bf16x8 As, Ab;
        #pragma unroll
        for (int j = 0; j < 8; ++j) {
            As[j] = (short)f2bf(sideL[m][k0 + j]);
            Ab[j] = (short)f2bf(biL[m][k0 + j]);
        }
        bf16x8 Bg = wf[(((layer * 2 + 0) * 2 + ks) * 4 + wave) * 64 + lane];
        bf16x8 Bb = wf[(((layer * 2 + 1) * 2 + ks) * 4 + wave) * 64 + lane];
        acc = __builtin_amdgcn_mfma_f32_16x16x32_bf16(As, Bg, acc, 0, 0, 0);
        acc = __builtin_amdgcn_mfma_f32_16x16x32_bf16(Ab, Bb, acc, 0, 0, 0);
    }

    const int col = wave * 16 + m;
    const float bs = bias[layer * 64 + col];
    #pragma unroll
    for (int i = 0; i < 4; ++i) {
        int nd = kh * 4 + i;                     // C row = node in block
        float o = acc[i] + bs;
        o = o > 0.f ? o : NEG_SLOPE * o;
        dst[(size_t)(blockIdx.x * 16 + nd) * 64 + col] = f2bf(o);
    }
}

// --------------------------------------------- batch GMF partial accumulation
__global__ void ngcf_batch(const int* __restrict__ uidx,
                           const int* __restrict__ iidx,
                           const u16* __restrict__ ego,
                           const float* __restrict__ Wout,
                           float* __restrict__ partial,
                           int layer, int normalize) {
    int b = blockIdx.x * (blockDim.x >> 6) + (threadIdx.x >> 6);
    int lane = threadIdx.x & 63;
    if (b >= BATCH) return;
    int u  = uidx[b];
    int it = N_USER + iidx[b];
    float eu = bf2f(ego[((size_t)u  << 6) + lane]);
    float ei = bf2f(ego[((size_t)it << 6) + lane]);
    float w  = Wout[(layer << 6) + lane];
    float dot = eu * ei * w;
    float nu = eu * eu, ni = ei * ei;
    #pragma unroll
    for (int off = 32; off; off >>= 1) {
        dot += __shfl_xor(dot, off);
        nu  += __shfl_xor(nu,  off);
        ni  += __shfl_xor(ni,  off);
    }
    if (lane == 0) {
        float val;
        if (normalize) {
            float denom = fmaxf(sqrtf(nu), 1e-12f) * fmaxf(sqrtf(ni), 1e-12f);
            val = dot / denom;
        } else {
            val = dot;
        }
        if (layer == 0) partial[b] = val;
        else            partial[b] += val;
    }
}

// ----------------------------------------------------------------- sigmoid
__global__ void ngcf_final(const float* __restrict__ partial,
                           const float* __restrict__ bout,
                           float* __restrict__ out) {
    int b = blockIdx.x * blockDim.x + threadIdx.x;
    if (b < BATCH) {
        float x = partial[b] + bout[0];
        out[b] = 1.f / (1.f + expf(-x));
    }
}

extern "C" void kernel_launch(void* const* d_in, const int* in_sizes, int n_in,
                              void* d_out, int out_size, void* d_ws, size_t ws_size,
                              hipStream_t stream) {
    const int*   user_idx = (const int*)  d_in[0];
    const int*   item_idx = (const int*)  d_in[1];
    const int*   adj_rows = (const int*)  d_in[2];
    const int*   adj_cols = (const int*)  d_in[3];
    const float* adj_vals = (const float*)d_in[4];
    const float* user_emb = (const float*)d_in[5];
    const float* item_emb = (const float*)d_in[6];
    const float* W_gc     = (const float*)d_in[7];
    const float* b_gc     = (const float*)d_in[8];
    const float* W_bi     = (const float*)d_in[9];
    const float* b_bi     = (const float*)d_in[10];
    const float* W_out    = (const float*)d_in[11];
    const float* b_out    = (const float*)d_in[12];
    float* out = (float*)d_out;

    const size_t NODE_F = (size_t)N_NODES * EMB;   // 9.6M elems

    char* base = (char*)d_ws;
    size_t off = 0;
    auto carve = [&](size_t bytes) {
        char* p = base + off;
        off = (off + bytes + 255) & ~(size_t)255;
        return p;
    };
    u16*   ego0    = (u16*)  carve(NODE_F * 2);
    u16*   ego1    = (u16*)  carve(NODE_F * 2);
    int2*  edges   = (int2*) carve((size_t)NNZ * 8);
    int2*  tmp_cv  = (int2*) carve((size_t)NNZ * 8);
    u16*   tmp_lr  = (u16*)  carve((size_t)NNZ * 2);
    int*   offs    = (int*)  carve((N_NODES + 1) * 4);
    int*   ccnt    = (int*)  carve(NB_C * 4);
    int*   coffs   = (int*)  carve((NB_C + 1) * 4);
    int*   gcursor = (int*)  carve(NB_C * 4);
    u16*   wfrag   = (u16*)  carve(WFRAG_ELEMS * 2);
    float* bias    = (float*)carve(3 * 64 * 4);
    float* partial = (float*)carve(BATCH * 4);
    (void)ws_size;

    ngcf_concat<<<(N_NODES * EMB / 4 + 255) / 256, 256, 0, stream>>>(
        (const float4*)user_emb, (const float4*)item_emb, (ushort4*)ego0);

    ngcf_prep<<<(WFRAG_ELEMS + 3 * 64 + 255) / 256, 256, 0, stream>>>(
        W_gc, W_bi, b_gc, b_bi, wfrag, bias);

    hipMemsetAsync(ccnt, 0, NB_C * sizeof(int), stream);
    ngcf_coarse_hist   <<<1024, 256, 0, stream>>>(adj_rows, ccnt);
    ngcf_coarse_scan   <<<1, NB_C, 0, stream>>>(ccnt, coffs, gcursor);
    ngcf_coarse_scatter<<<NCH, 512, 0, stream>>>(adj_rows, adj_cols, adj_vals,
                                                 gcursor, tmp_cv, tmp_lr);
    ngcf_fine_sort     <<<NB_C, 512, 0, stream>>>(coffs, tmp_cv, tmp_lr,
                                                  offs, edges);

    ngcf_batch<<<BATCH / 4, 256, 0, stream>>>(user_idx, item_idx, ego0,
                                              W_out, partial, 0, 0);

    u16* src = ego0;
    u16* dst = ego1;
    for (int k = 0; k < 3; ++k) {
        ngcf_spmm_mfma<<<N_NODES / 16, 256, 0, stream>>>(
            src, dst, offs, edges, wfrag, bias, k);
        ngcf_batch<<<BATCH / 4, 256, 0, stream>>>(user_idx, item_idx, dst,
                                                  W_out, partial, k + 1, 1);
        u16* t = src; src = dst; dst = t;
    }
    ngcf_final<<<(BATCH + 255) / 256, 256, 0, stream>>>(partial, b_out, out);
}

// Round 7
// 696.917 us; speedup vs baseline: 18.0522x; 1.6478x over previous
//
#include <hip/hip_runtime.h>

#define N_USER  100000
#define N_ITEM  50000
#define N_NODES 150000
#define NNZ     4800000
#define EMB     64
#define BATCH   16384
#define NEG_SLOPE 0.2f

#define NB_C   512                       // coarse buckets
#define NPB    ((N_NODES + NB_C - 1) / NB_C)   // 293 nodes per bucket
#define CHUNK  8192                      // edges per coarse_scatter block
#define NCH    ((NNZ + CHUNK - 1) / CHUNK)     // 586

#define WFRAG_ELEMS (3 * 2 * 2 * 4 * 64 * 8)   // layer,mat,ks,wave,lane,i

typedef unsigned int  uint;
typedef unsigned short u16;
typedef short bf16x8 __attribute__((ext_vector_type(8)));
typedef float f32x4  __attribute__((ext_vector_type(4)));

static __device__ __forceinline__ u16 f2bf(float f) {
    uint u = __float_as_uint(f);
    return (u16)((u + 0x7fffu + ((u >> 16) & 1u)) >> 16);   // RNE
}
static __device__ __forceinline__ float bf2f(u16 h) {
    return __uint_as_float((uint)h << 16);
}

// ---------------------------------------------------- concat ego (f32->bf16)
__global__ void ngcf_concat(const float4* __restrict__ ue,
                            const float4* __restrict__ ie,
                            ushort4* __restrict__ ego) {
    const int n4_user  = N_USER * EMB / 4;
    const int n4_total = N_NODES * EMB / 4;
    int i = blockIdx.x * blockDim.x + threadIdx.x;
    if (i >= n4_total) return;
    float4 v = (i < n4_user) ? ue[i] : ie[i - n4_user];
    ushort4 o;
    o.x = f2bf(v.x); o.y = f2bf(v.y); o.z = f2bf(v.z); o.w = f2bf(v.w);
    ego[i] = o;
}

// ------------- prep: W -> bf16 fragments in MFMA B-layout; bias = bgc + bbi
__global__ void ngcf_prep(const float* __restrict__ Wgc,
                          const float* __restrict__ Wbi,
                          const float* __restrict__ bgc,
                          const float* __restrict__ bbi,
                          u16* __restrict__ wfrag, float* __restrict__ bias) {
    int t = blockIdx.x * blockDim.x + threadIdx.x;
    if (t < WFRAG_ELEMS) {
        int i     = t & 7;
        int lane  = (t >> 3) & 63;
        int w     = (t >> 9) & 3;
        int ks    = (t >> 11) & 1;
        int mat   = (t >> 12) & 1;
        int layer = t >> 13;
        int k = ks * 32 + (lane >> 4) * 8 + i;
        int n = w * 16 + (lane & 15);
        const float* W = mat ? Wbi : Wgc;
        wfrag[t] = f2bf(W[(layer * 64 + k) * 64 + n]);
    }
    int u = t - WFRAG_ELEMS;
    if (u >= 0 && u < 3 * 64)
        bias[u] = bgc[u] + bbi[u];
}

// ------------------------------------------- coarse histogram (LDS-aggregated)
__global__ void ngcf_coarse_hist(const int* __restrict__ rows,
                                 int* __restrict__ ccnt) {
    __shared__ int bins[NB_C];
    bins[threadIdx.x] = 0;
    bins[threadIdx.x + 256] = 0;
    __syncthreads();
    int stride = gridDim.x * blockDim.x;
    for (int e = blockIdx.x * blockDim.x + threadIdx.x; e < NNZ; e += stride)
        atomicAdd(&bins[rows[e] / NPB], 1);
    __syncthreads();
    int v0 = bins[threadIdx.x], v1 = bins[threadIdx.x + 256];
    if (v0) atomicAdd(&ccnt[threadIdx.x], v0);
    if (v1) atomicAdd(&ccnt[threadIdx.x + 256], v1);
}

// ------------------------------------ scan of 512 coarse counts (one block)
__global__ void ngcf_coarse_scan(const int* __restrict__ ccnt,
                                 int* __restrict__ coffs,
                                 int* __restrict__ gcursor) {
    __shared__ int wsum[8];
    int t = threadIdx.x, lane = t & 63, wv = t >> 6;
    int v = ccnt[t];
    int inc = v;
    #pragma unroll
    for (int off = 1; off < 64; off <<= 1) {
        int u = __shfl_up(inc, off);
        if (lane >= off) inc += u;
    }
    if (lane == 63) wsum[wv] = inc;
    __syncthreads();
    int base = 0;
    #pragma unroll
    for (int w = 0; w < 8; ++w) base += (w < wv) ? wsum[w] : 0;
    int incl = base + inc;
    int excl = incl - v;
    coffs[t]   = excl;
    gcursor[t] = excl;
    if (t == NB_C - 1) coffs[NB_C] = incl;     // == NNZ
}

// ---------------- coarse scatter: chunk-binned, run-reserved, locally written
__global__ __launch_bounds__(512) void ngcf_coarse_scatter(
        const int* __restrict__ rows, const int* __restrict__ cols,
        const float* __restrict__ vals,
        int* __restrict__ gcursor,
        int2* __restrict__ tmp_cv, u16* __restrict__ tmp_lr) {
    __shared__ int bins[NB_C];
    __shared__ int rbase[NB_C];
    const int t = threadIdx.x;
    const int e0 = blockIdx.x * CHUNK;
    bins[t] = 0;
    __syncthreads();
    #pragma unroll
    for (int i = 0; i < CHUNK / 512; ++i) {
        int e = e0 + i * 512 + t;
        if (e < NNZ) atomicAdd(&bins[rows[e] / NPB], 1);
    }
    __syncthreads();
    int c = bins[t];
    if (c > 0) rbase[t] = atomicAdd(&gcursor[t], c);
    bins[t] = 0;
    __syncthreads();
    #pragma unroll
    for (int i = 0; i < CHUNK / 512; ++i) {
        int e = e0 + i * 512 + t;
        if (e < NNZ) {
            int r  = rows[e];
            int b  = r / NPB;
            int lr = r - b * NPB;
            int rk = atomicAdd(&bins[b], 1);
            int pos = rbase[b] + rk;
            int2 E; E.x = cols[e]; E.y = __float_as_int(vals[e]);
            tmp_cv[pos] = E;
            tmp_lr[pos] = (u16)lr;
        }
    }
}

// -------------- fine sort: one block per coarse bucket, node-level ordering
__global__ __launch_bounds__(512) void ngcf_fine_sort(
        const int* __restrict__ coffs,
        const int2* __restrict__ tmp_cv, const u16* __restrict__ tmp_lr,
        int* __restrict__ offs, int2* __restrict__ edges) {
    __shared__ int s[512];
    const int b   = blockIdx.x;
    const int t   = threadIdx.x;
    const int nlo = b * NPB;
    const int nhi = min(nlo + NPB, N_NODES);
    const int nn  = nhi - nlo;
    const int clo = coffs[b];
    const int chi = coffs[b + 1];

    s[t] = 0;
    __syncthreads();
    for (int e = clo + t; e < chi; e += 512)
        atomicAdd(&s[tmp_lr[e]], 1);
    __syncthreads();
    int v = s[t];
    for (int d = 1; d < 512; d <<= 1) {
        int u = (t >= d) ? s[t - d] : 0;
        __syncthreads();
        s[t] += u;
        __syncthreads();
    }
    int excl = s[t] - v;
    if (t < nn) offs[nlo + t] = clo + excl;
    __syncthreads();
    s[t] = clo + excl;
    __syncthreads();
    for (int e = clo + t; e < chi; e += 512) {
        int lr = tmp_lr[e];
        int p  = atomicAdd(&s[lr], 1);
        edges[p] = tmp_cv[e];
    }
    if (b == NB_C - 1 && t == 0) offs[N_NODES] = chi;
}

// ---------------- fused gather-SpMM + MFMA transform (16 nodes per block)
// Gather: 16-lane group per node; 16-edge chunks loaded cooperatively
// (one coalesced 128B load), shfl-broadcast, 16 src-row loads in flight.
__global__ __launch_bounds__(256) void ngcf_spmm_mfma(
        const u16* __restrict__ src, u16* __restrict__ dst,
        const int* __restrict__ offs, const int2* __restrict__ edges,
        const u16* __restrict__ wfrag, const float* __restrict__ bias,
        int layer) {
    __shared__ float sideL[16][68];
    __shared__ float biL[16][68];

    const int wave = threadIdx.x >> 6;
    const int lane = threadIdx.x & 63;
    const int g    = lane >> 4;        // node group 0..3
    const int q    = lane & 15;        // dim quad: dims 4q..4q+3
    const int node = blockIdx.x * 16 + wave * 4 + g;

    const int sBeg = offs[node];
    const int deg  = offs[node + 1] - sBeg;

    const long long* ep  = (const long long*)edges;
    const ushort4*   s4p = (const ushort4*)src;

    float a0 = 0.f, a1 = 0.f, a2 = 0.f, a3 = 0.f;
    for (int base = 0; __any(base < deg); base += 16) {
        // cooperative chunk load: lane q takes edge base+q (coalesced 128B)
        int idx = base + q;
        long long L = 0;
        if (idx < deg) L = __builtin_nontemporal_load(ep + sBeg + idx);
        int Ec = (int)L;
        int Ev = (int)(L >> 32);
        // process the 16 edges of this group's chunk; pads are (c=0, v=0)
        #pragma unroll
        for (int j = 0; j < 16; ++j) {
            int   c = __shfl(Ec, (g << 4) + j);
            float v = __int_as_float(__shfl(Ev, (g << 4) + j));
            ushort4 s4 = s4p[(size_t)c * 16 + q];
            a0 += v * bf2f(s4.x);
            a1 += v * bf2f(s4.y);
            a2 += v * bf2f(s4.z);
            a3 += v * bf2f(s4.w);
        }
    }

    ushort4 egov = s4p[(size_t)node * 16 + q];
    const int r = wave * 4 + g;
    float4 sv; sv.x = a0; sv.y = a1; sv.z = a2; sv.w = a3;
    float4 bv; bv.x = bf2f(egov.x) * a0; bv.y = bf2f(egov.y) * a1;
    bv.z = bf2f(egov.z) * a2; bv.w = bf2f(egov.w) * a3;
    *(float4*)&sideL[r][4 * q] = sv;
    *(float4*)&biL[r][4 * q]   = bv;
    __syncthreads();

    // ---- MFMA transform: wave covers out-cols [wave*16, wave*16+16)
    const int m  = lane & 15;          // A row (node) held by this lane
    const int kh = lane >> 4;          // k-half index
    f32x4 acc = {0.f, 0.f, 0.f, 0.f};
    const bf16x8* wf = (const bf16x8*)wfrag;

    #pragma unroll
    for (int ks = 0; ks < 2; ++ks) {
        const int k0 = ks * 32 + kh * 8;
        bf16x8 As, Ab;
        #pragma unroll
        for (int j = 0; j < 8; ++j) {
            As[j] = (short)f2bf(sideL[m][k0 + j]);
            Ab[j] = (short)f2bf(biL[m][k0 + j]);
        }
        bf16x8 Bg = wf[(((layer * 2 + 0) * 2 + ks) * 4 + wave) * 64 + lane];
        bf16x8 Bb = wf[(((layer * 2 + 1) * 2 + ks) * 4 + wave) * 64 + lane];
        acc = __builtin_amdgcn_mfma_f32_16x16x32_bf16(As, Bg, acc, 0, 0, 0);
        acc = __builtin_amdgcn_mfma_f32_16x16x32_bf16(Ab, Bb, acc, 0, 0, 0);
    }

    const int col = wave * 16 + m;
    const float bs = bias[layer * 64 + col];
    #pragma unroll
    for (int i = 0; i < 4; ++i) {
        int nd = kh * 4 + i;                     // C row = node in block
        float o = acc[i] + bs;
        o = o > 0.f ? o : NEG_SLOPE * o;
        dst[(size_t)(blockIdx.x * 16 + nd) * 64 + col] = f2bf(o);
    }
}

// --------------------------------------------- batch GMF partial accumulation
__global__ void ngcf_batch(const int* __restrict__ uidx,
                           const int* __restrict__ iidx,
                           const u16* __restrict__ ego,
                           const float* __restrict__ Wout,
                           float* __restrict__ partial,
                           int layer, int normalize) {
    int b = blockIdx.x * (blockDim.x >> 6) + (threadIdx.x >> 6);
    int lane = threadIdx.x & 63;
    if (b >= BATCH) return;
    int u  = uidx[b];
    int it = N_USER + iidx[b];
    float eu = bf2f(ego[((size_t)u  << 6) + lane]);
    float ei = bf2f(ego[((size_t)it << 6) + lane]);
    float w  = Wout[(layer << 6) + lane];
    float dot = eu * ei * w;
    float nu = eu * eu, ni = ei * ei;
    #pragma unroll
    for (int off = 32; off; off >>= 1) {
        dot += __shfl_xor(dot, off);
        nu  += __shfl_xor(nu,  off);
        ni  += __shfl_xor(ni,  off);
    }
    if (lane == 0) {
        float val;
        if (normalize) {
            float denom = fmaxf(sqrtf(nu), 1e-12f) * fmaxf(sqrtf(ni), 1e-12f);
            val = dot / denom;
        } else {
            val = dot;
        }
        if (layer == 0) partial[b] = val;
        else            partial[b] += val;
    }
}

// ----------------------------------------------------------------- sigmoid
__global__ void ngcf_final(const float* __restrict__ partial,
                           const float* __restrict__ bout,
                           float* __restrict__ out) {
    int b = blockIdx.x * blockDim.x + threadIdx.x;
    if (b < BATCH) {
        float x = partial[b] + bout[0];
        out[b] = 1.f / (1.f + expf(-x));
    }
}

extern "C" void kernel_launch(void* const* d_in, const int* in_sizes, int n_in,
                              void* d_out, int out_size, void* d_ws, size_t ws_size,
                              hipStream_t stream) {
    const int*   user_idx = (const int*)  d_in[0];
    const int*   item_idx = (const int*)  d_in[1];
    const int*   adj_rows = (const int*)  d_in[2];
    const int*   adj_cols = (const int*)  d_in[3];
    const float* adj_vals = (const float*)d_in[4];
    const float* user_emb = (const float*)d_in[5];
    const float* item_emb = (const float*)d_in[6];
    const float* W_gc     = (const float*)d_in[7];
    const float* b_gc     = (const float*)d_in[8];
    const float* W_bi     = (const float*)d_in[9];
    const float* b_bi     = (const float*)d_in[10];
    const float* W_out    = (const float*)d_in[11];
    const float* b_out    = (const float*)d_in[12];
    float* out = (float*)d_out;

    const size_t NODE_F = (size_t)N_NODES * EMB;   // 9.6M elems

    char* base = (char*)d_ws;
    size_t off = 0;
    auto carve = [&](size_t bytes) {
        char* p = base + off;
        off = (off + bytes + 255) & ~(size_t)255;
        return p;
    };
    u16*   ego0    = (u16*)  carve(NODE_F * 2);
    u16*   ego1    = (u16*)  carve(NODE_F * 2);
    int2*  edges   = (int2*) carve((size_t)NNZ * 8);
    int2*  tmp_cv  = (int2*) carve((size_t)NNZ * 8);
    u16*   tmp_lr  = (u16*)  carve((size_t)NNZ * 2);
    int*   offs    = (int*)  carve((N_NODES + 1) * 4);
    int*   ccnt    = (int*)  carve(NB_C * 4);
    int*   coffs   = (int*)  carve((NB_C + 1) * 4);
    int*   gcursor = (int*)  carve(NB_C * 4);
    u16*   wfrag   = (u16*)  carve(WFRAG_ELEMS * 2);
    float* bias    = (float*)carve(3 * 64 * 4);
    float* partial = (float*)carve(BATCH * 4);
    (void)ws_size;

    ngcf_concat<<<(N_NODES * EMB / 4 + 255) / 256, 256, 0, stream>>>(
        (const float4*)user_emb, (const float4*)item_emb, (ushort4*)ego0);

    ngcf_prep<<<(WFRAG_ELEMS + 3 * 64 + 255) / 256, 256, 0, stream>>>(
        W_gc, W_bi, b_gc, b_bi, wfrag, bias);

    hipMemsetAsync(ccnt, 0, NB_C * sizeof(int), stream);
    ngcf_coarse_hist   <<<1024, 256, 0, stream>>>(adj_rows, ccnt);
    ngcf_coarse_scan   <<<1, NB_C, 0, stream>>>(ccnt, coffs, gcursor);
    ngcf_coarse_scatter<<<NCH, 512, 0, stream>>>(adj_rows, adj_cols, adj_vals,
                                                 gcursor, tmp_cv, tmp_lr);
    ngcf_fine_sort     <<<NB_C, 512, 0, stream>>>(coffs, tmp_cv, tmp_lr,
                                                  offs, edges);

    ngcf_batch<<<BATCH / 4, 256, 0, stream>>>(user_idx, item_idx, ego0,
                                              W_out, partial, 0, 0);

    u16* src = ego0;
    u16* dst = ego1;
    for (int k = 0; k < 3; ++k) {
        ngcf_spmm_mfma<<<N_NODES / 16, 256, 0, stream>>>(
            src, dst, offs, edges, wfrag, bias, k);
        ngcf_batch<<<BATCH / 4, 256, 0, stream>>>(user_idx, item_idx, dst,
                                                  W_out, partial, k + 1, 1);
        u16* t = src; src = dst; dst = t;
    }
    ngcf_final<<<(BATCH + 255) / 256, 256, 0, stream>>>(partial, b_out, out);
}

// Round 8
// 559.775 us; speedup vs baseline: 22.4750x; 1.2450x over previous
//
#include <hip/hip_runtime.h>

#define N_USER  100000
#define N_ITEM  50000
#define N_NODES 150000
#define NNZ     4800000
#define EMB     64
#define BATCH   16384
#define NEG_SLOPE 0.2f

#define NB_C   512                       // coarse buckets
#define NPB    ((N_NODES + NB_C - 1) / NB_C)   // 293 nodes per bucket
#define CHUNK  6144                      // edges per coarse_scatter block (LDS-staged)
#define NCH    ((NNZ + CHUNK - 1) / CHUNK)

#define WFRAG_ELEMS (3 * 2 * 2 * 4 * 64 * 8)   // layer,mat,ks,wave,lane,i

typedef unsigned int  uint;
typedef unsigned short u16;
typedef unsigned long long u64;
typedef short bf16x8 __attribute__((ext_vector_type(8)));
typedef float f32x4  __attribute__((ext_vector_type(4)));

static __device__ __forceinline__ u16 f2bf(float f) {
    uint u = __float_as_uint(f);
    return (u16)((u + 0x7fffu + ((u >> 16) & 1u)) >> 16);   // RNE
}
static __device__ __forceinline__ float bf2f(u16 h) {
    return __uint_as_float((uint)h << 16);
}

// ---------------------------------------------------- concat ego (f32->bf16)
__global__ void ngcf_concat(const float4* __restrict__ ue,
                            const float4* __restrict__ ie,
                            ushort4* __restrict__ ego) {
    const int n4_user  = N_USER * EMB / 4;
    const int n4_total = N_NODES * EMB / 4;
    int i = blockIdx.x * blockDim.x + threadIdx.x;
    if (i >= n4_total) return;
    float4 v = (i < n4_user) ? ue[i] : ie[i - n4_user];
    ushort4 o;
    o.x = f2bf(v.x); o.y = f2bf(v.y); o.z = f2bf(v.z); o.w = f2bf(v.w);
    ego[i] = o;
}

// ------------- prep: W -> bf16 fragments in MFMA B-layout; bias = bgc + bbi
__global__ void ngcf_prep(const float* __restrict__ Wgc,
                          const float* __restrict__ Wbi,
                          const float* __restrict__ bgc,
                          const float* __restrict__ bbi,
                          u16* __restrict__ wfrag, float* __restrict__ bias) {
    int t = blockIdx.x * blockDim.x + threadIdx.x;
    if (t < WFRAG_ELEMS) {
        int i     = t & 7;
        int lane  = (t >> 3) & 63;
        int w     = (t >> 9) & 3;
        int ks    = (t >> 11) & 1;
        int mat   = (t >> 12) & 1;
        int layer = t >> 13;
        int k = ks * 32 + (lane >> 4) * 8 + i;
        int n = w * 16 + (lane & 15);
        const float* W = mat ? Wbi : Wgc;
        wfrag[t] = f2bf(W[(layer * 64 + k) * 64 + n]);
    }
    int u = t - WFRAG_ELEMS;
    if (u >= 0 && u < 3 * 64)
        bias[u] = bgc[u] + bbi[u];
}

// ------------------------------------------- coarse histogram (LDS-aggregated)
__global__ void ngcf_coarse_hist(const int* __restrict__ rows,
                                 int* __restrict__ ccnt) {
    __shared__ int bins[NB_C];
    bins[threadIdx.x] = 0;
    bins[threadIdx.x + 256] = 0;
    __syncthreads();
    int stride = gridDim.x * blockDim.x;
    for (int e = blockIdx.x * blockDim.x + threadIdx.x; e < NNZ; e += stride)
        atomicAdd(&bins[rows[e] / NPB], 1);
    __syncthreads();
    int v0 = bins[threadIdx.x], v1 = bins[threadIdx.x + 256];
    if (v0) atomicAdd(&ccnt[threadIdx.x], v0);
    if (v1) atomicAdd(&ccnt[threadIdx.x + 256], v1);
}

// ------------------------------------ scan of 512 coarse counts (one block)
__global__ void ngcf_coarse_scan(const int* __restrict__ ccnt,
                                 int* __restrict__ coffs,
                                 int* __restrict__ gcursor) {
    __shared__ int wsum[8];
    int t = threadIdx.x, lane = t & 63, wv = t >> 6;
    int v = ccnt[t];
    int inc = v;
    #pragma unroll
    for (int off = 1; off < 64; off <<= 1) {
        int u = __shfl_up(inc, off);
        if (lane >= off) inc += u;
    }
    if (lane == 63) wsum[wv] = inc;
    __syncthreads();
    int base = 0;
    #pragma unroll
    for (int w = 0; w < 8; ++w) base += (w < wv) ? wsum[w] : 0;
    int incl = base + inc;
    int excl = incl - v;
    coffs[t]   = excl;
    gcursor[t] = excl;
    if (t == NB_C - 1) coffs[NB_C] = incl;     // == NNZ
}

// -------- coarse scatter v2: LDS-staged, run-coalesced writes, packed u64
// pack: [63:32]=val bits, [26:9]=col (18b), [8:0]=local row in bucket (9b)
__global__ __launch_bounds__(512) void ngcf_coarse_scatter(
        const int* __restrict__ rows, const int* __restrict__ cols,
        const float* __restrict__ vals,
        int* __restrict__ gcursor,
        u64* __restrict__ tmp) {
    __shared__ int bins[NB_C];
    __shared__ int lbase_s[NB_C + 1];
    __shared__ int delta_s[NB_C];
    __shared__ int wsum[8];
    __shared__ u64 stage[CHUNK];          // 48 KB

    const int t  = threadIdx.x;
    const int e0 = blockIdx.x * CHUNK;
    const int cnt = min(CHUNK, NNZ - e0);

    bins[t] = 0;
    __syncthreads();
    // phase A: count
    #pragma unroll
    for (int i = 0; i < CHUNK / 512; ++i) {
        int e = e0 + i * 512 + t;
        if (e < NNZ) atomicAdd(&bins[rows[e] / NPB], 1);
    }
    __syncthreads();
    // phase B: local scan + global run reservation
    int v = bins[t];
    int lane = t & 63, wv = t >> 6;
    int inc = v;
    #pragma unroll
    for (int off = 1; off < 64; off <<= 1) {
        int u = __shfl_up(inc, off);
        if (lane >= off) inc += u;
    }
    if (lane == 63) wsum[wv] = inc;
    __syncthreads();
    int base = 0;
    #pragma unroll
    for (int w = 0; w < 8; ++w) base += (w < wv) ? wsum[w] : 0;
    int incl = base + inc;
    int excl = incl - v;
    lbase_s[t] = excl;
    if (t == NB_C - 1) lbase_s[NB_C] = incl;
    int myrbase = (v > 0) ? atomicAdd(&gcursor[t], v) : 0;
    delta_s[t] = myrbase - excl;          // global = delta[b] + local_slot
    bins[t] = 0;                          // becomes rank counter
    __syncthreads();
    // phase C: rank & stage into LDS (bucket-sorted within chunk)
    #pragma unroll
    for (int i = 0; i < CHUNK / 512; ++i) {
        int e = e0 + i * 512 + t;
        if (e < NNZ) {
            int r  = rows[e];
            int b  = r / NPB;
            int lr = r - b * NPB;
            int rk = atomicAdd(&bins[b], 1);
            u64 P = ((u64)(uint)__float_as_int(vals[e]) << 32)
                  | ((uint)cols[e] << 9) | (uint)lr;
            stage[lbase_s[b] + rk] = P;
        }
    }
    __syncthreads();
    // phase D: linear LDS walk -> run-coalesced global writes
    for (int i = t; i < cnt; i += 512) {
        // largest b with lbase_s[b] <= i  (9-step binary search in LDS)
        int b = 0;
        #pragma unroll
        for (int s = 256; s >= 1; s >>= 1) {
            int nb = b + s;
            if (nb <= NB_C - 1 && lbase_s[nb] <= i) b = nb;
        }
        tmp[delta_s[b] + i] = stage[i];
    }
}

// -------------- fine sort: one block per coarse bucket, node-level ordering
__global__ __launch_bounds__(512) void ngcf_fine_sort(
        const int* __restrict__ coffs,
        const u64* __restrict__ tmp,
        int* __restrict__ offs, int2* __restrict__ edges) {
    __shared__ int s[512];
    const int b   = blockIdx.x;
    const int t   = threadIdx.x;
    const int nlo = b * NPB;
    const int nhi = min(nlo + NPB, N_NODES);
    const int nn  = nhi - nlo;
    const int clo = coffs[b];
    const int chi = coffs[b + 1];

    s[t] = 0;
    __syncthreads();
    for (int e = clo + t; e < chi; e += 512)
        atomicAdd(&s[(int)(tmp[e] & 511u)], 1);
    __syncthreads();
    int v = s[t];
    for (int d = 1; d < 512; d <<= 1) {
        int u = (t >= d) ? s[t - d] : 0;
        __syncthreads();
        s[t] += u;
        __syncthreads();
    }
    int excl = s[t] - v;
    if (t < nn) offs[nlo + t] = clo + excl;
    __syncthreads();
    s[t] = clo + excl;
    __syncthreads();
    for (int e = clo + t; e < chi; e += 512) {
        u64 P  = tmp[e];
        int lr = (int)(P & 511u);
        int p  = atomicAdd(&s[lr], 1);
        int2 E;
        E.x = (int)((P >> 9) & 0x3FFFFu);
        E.y = (int)(P >> 32);
        edges[p] = E;
    }
    if (b == NB_C - 1 && t == 0) offs[N_NODES] = chi;
}

// ---------------- fused gather-SpMM + MFMA transform (16 nodes per block)
__global__ __launch_bounds__(256) void ngcf_spmm_mfma(
        const u16* __restrict__ src, u16* __restrict__ dst,
        const int* __restrict__ offs, const int2* __restrict__ edges,
        const u16* __restrict__ wfrag, const float* __restrict__ bias,
        int layer) {
    __shared__ float sideL[16][68];
    __shared__ float biL[16][68];

    const int wave = threadIdx.x >> 6;
    const int lane = threadIdx.x & 63;
    const int g    = lane >> 4;        // node group 0..3
    const int q    = lane & 15;        // dim quad: dims 4q..4q+3
    const int node = blockIdx.x * 16 + wave * 4 + g;

    const int sBeg = offs[node];
    const int deg  = offs[node + 1] - sBeg;

    const long long* ep  = (const long long*)edges;
    const ushort4*   s4p = (const ushort4*)src;

    float a0 = 0.f, a1 = 0.f, a2 = 0.f, a3 = 0.f;
    for (int base = 0; __any(base < deg); base += 16) {
        int idx = base + q;
        long long L = 0;
        if (idx < deg) L = __builtin_nontemporal_load(ep + sBeg + idx);
        int Ec = (int)L;
        int Ev = (int)(L >> 32);
        #pragma unroll
        for (int j = 0; j < 16; ++j) {
            int   c = __shfl(Ec, (g << 4) + j);
            float v = __int_as_float(__shfl(Ev, (g << 4) + j));
            ushort4 s4 = s4p[(size_t)c * 16 + q];
            a0 += v * bf2f(s4.x);
            a1 += v * bf2f(s4.y);
            a2 += v * bf2f(s4.z);
            a3 += v * bf2f(s4.w);
        }
    }

    ushort4 egov = s4p[(size_t)node * 16 + q];
    const int r = wave * 4 + g;
    float4 sv; sv.x = a0; sv.y = a1; sv.z = a2; sv.w = a3;
    float4 bv; bv.x = bf2f(egov.x) * a0; bv.y = bf2f(egov.y) * a1;
    bv.z = bf2f(egov.z) * a2; bv.w = bf2f(egov.w) * a3;
    *(float4*)&sideL[r][4 * q] = sv;
    *(float4*)&biL[r][4 * q]   = bv;
    __syncthreads();

    const int m  = lane & 15;          // A row (node) held by this lane
    const int kh = lane >> 4;          // k-half index
    f32x4 acc = {0.f, 0.f, 0.f, 0.f};
    const bf16x8* wf = (const bf16x8*)wfrag;

    #pragma unroll
    for (int ks = 0; ks < 2; ++ks) {
        const int k0 = ks * 32 + kh * 8;
        bf16x8 As, Ab;
        #pragma unroll
        for (int j = 0; j < 8; ++j) {
            As[j] = (short)f2bf(sideL[m][k0 + j]);
            Ab[j] = (short)f2bf(biL[m][k0 + j]);
        }
        bf16x8 Bg = wf[(((layer * 2 + 0) * 2 + ks) * 4 + wave) * 64 + lane];
        bf16x8 Bb = wf[(((layer * 2 + 1) * 2 + ks) * 4 + wave) * 64 + lane];
        acc = __builtin_amdgcn_mfma_f32_16x16x32_bf16(As, Bg, acc, 0, 0, 0);
        acc = __builtin_amdgcn_mfma_f32_16x16x32_bf16(Ab, Bb, acc, 0, 0, 0);
    }

    const int col = wave * 16 + m;
    const float bs = bias[layer * 64 + col];
    #pragma unroll
    for (int i = 0; i < 4; ++i) {
        int nd = kh * 4 + i;                     // C row = node in block
        float o = acc[i] + bs;
        o = o > 0.f ? o : NEG_SLOPE * o;
        dst[(size_t)(blockIdx.x * 16 + nd) * 64 + col] = f2bf(o);
    }
}

// --------------------------------------------- batch GMF partial accumulation
__global__ void ngcf_batch(const int* __restrict__ uidx,
                           const int* __restrict__ iidx,
                           const u16* __restrict__ ego,
                           const float* __restrict__ Wout,
                           float* __restrict__ partial,
                           int layer, int normalize) {
    int b = blockIdx.x * (blockDim.x >> 6) + (threadIdx.x >> 6);
    int lane = threadIdx.x & 63;
    if (b >= BATCH) return;
    int u  = uidx[b];
    int it = N_USER + iidx[b];
    float eu = bf2f(ego[((size_t)u  << 6) + lane]);
    float ei = bf2f(ego[((size_t)it << 6) + lane]);
    float w  = Wout[(layer << 6) + lane];
    float dot = eu * ei * w;
    float nu = eu * eu, ni = ei * ei;
    #pragma unroll
    for (int off = 32; off; off >>= 1) {
        dot += __shfl_xor(dot, off);
        nu  += __shfl_xor(nu,  off);
        ni  += __shfl_xor(ni,  off);
    }
    if (lane == 0) {
        float val;
        if (normalize) {
            float denom = fmaxf(sqrtf(nu), 1e-12f) * fmaxf(sqrtf(ni), 1e-12f);
            val = dot / denom;
        } else {
            val = dot;
        }
        if (layer == 0) partial[b] = val;
        else            partial[b] += val;
    }
}

// ----------------------------------------------------------------- sigmoid
__global__ void ngcf_final(const float* __restrict__ partial,
                           const float* __restrict__ bout,
                           float* __restrict__ out) {
    int b = blockIdx.x * blockDim.x + threadIdx.x;
    if (b < BATCH) {
        float x = partial[b] + bout[0];
        out[b] = 1.f / (1.f + expf(-x));
    }
}

extern "C" void kernel_launch(void* const* d_in, const int* in_sizes, int n_in,
                              void* d_out, int out_size, void* d_ws, size_t ws_size,
                              hipStream_t stream) {
    const int*   user_idx = (const int*)  d_in[0];
    const int*   item_idx = (const int*)  d_in[1];
    const int*   adj_rows = (const int*)  d_in[2];
    const int*   adj_cols = (const int*)  d_in[3];
    const float* adj_vals = (const float*)d_in[4];
    const float* user_emb = (const float*)d_in[5];
    const float* item_emb = (const float*)d_in[6];
    const float* W_gc     = (const float*)d_in[7];
    const float* b_gc     = (const float*)d_in[8];
    const float* W_bi     = (const float*)d_in[9];
    const float* b_bi     = (const float*)d_in[10];
    const float* W_out    = (const float*)d_in[11];
    const float* b_out    = (const float*)d_in[12];
    float* out = (float*)d_out;

    const size_t NODE_F = (size_t)N_NODES * EMB;   // 9.6M elems

    char* base = (char*)d_ws;
    size_t off = 0;
    auto carve = [&](size_t bytes) {
        char* p = base + off;
        off = (off + bytes + 255) & ~(size_t)255;
        return p;
    };
    u16*   ego0    = (u16*)  carve(NODE_F * 2);
    u16*   ego1    = (u16*)  carve(NODE_F * 2);
    int2*  edges   = (int2*) carve((size_t)NNZ * 8);
    u64*   tmp     = (u64*)  carve((size_t)NNZ * 8);
    int*   offs    = (int*)  carve((N_NODES + 1) * 4);
    int*   ccnt    = (int*)  carve(NB_C * 4);
    int*   coffs   = (int*)  carve((NB_C + 1) * 4);
    int*   gcursor = (int*)  carve(NB_C * 4);
    u16*   wfrag   = (u16*)  carve(WFRAG_ELEMS * 2);
    float* bias    = (float*)carve(3 * 64 * 4);
    float* partial = (float*)carve(BATCH * 4);
    (void)ws_size;

    ngcf_concat<<<(N_NODES * EMB / 4 + 255) / 256, 256, 0, stream>>>(
        (const float4*)user_emb, (const float4*)item_emb, (ushort4*)ego0);

    ngcf_prep<<<(WFRAG_ELEMS + 3 * 64 + 255) / 256, 256, 0, stream>>>(
        W_gc, W_bi, b_gc, b_bi, wfrag, bias);

    hipMemsetAsync(ccnt, 0, NB_C * sizeof(int), stream);
    ngcf_coarse_hist   <<<1024, 256, 0, stream>>>(adj_rows, ccnt);
    ngcf_coarse_scan   <<<1, NB_C, 0, stream>>>(ccnt, coffs, gcursor);
    ngcf_coarse_scatter<<<NCH, 512, 0, stream>>>(adj_rows, adj_cols, adj_vals,
                                                 gcursor, tmp);
    ngcf_fine_sort     <<<NB_C, 512, 0, stream>>>(coffs, tmp, offs, edges);

    ngcf_batch<<<BATCH / 4, 256, 0, stream>>>(user_idx, item_idx, ego0,
                                              W_out, partial, 0, 0);

    u16* src = ego0;
    u16* dst = ego1;
    for (int k = 0; k < 3; ++k) {
        ngcf_spmm_mfma<<<N_NODES / 16, 256, 0, stream>>>(
            src, dst, offs, edges, wfrag, bias, k);
        ngcf_batch<<<BATCH / 4, 256, 0, stream>>>(user_idx, item_idx, dst,
                                                  W_out, partial, k + 1, 1);
        u16* t = src; src = dst; dst = t;
    }
    ngcf_final<<<(BATCH + 255) / 256, 256, 0, stream>>>(partial, b_out, out);
}